// Round 1
// baseline (711.053 us; speedup 1.0000x reference)
//
#include <hip/hip_runtime.h>

// Problem constants
#define NB    16
#define TLEN  1024
#define CCH   128      // channels
#define DR    320
#define GENL  98304    // 3*128*128*2

// ---------------------------------------------------------------------------
// Transpose x (N,T,C) -> h (N,C,T)
__global__ __launch_bounds__(256) void k_transpose(const float* __restrict__ x,
                                                   float* __restrict__ h) {
  __shared__ float tile[32][33];
  const int n  = blockIdx.z;
  const int t0 = blockIdx.x * 32;
  const int c0 = blockIdx.y * 32;
  const int tx = threadIdx.x, ty = threadIdx.y;
#pragma unroll
  for (int i = 0; i < 32; i += 8)
    tile[ty + i][tx] = x[((size_t)(n * TLEN + t0 + ty + i)) * CCH + c0 + tx];
  __syncthreads();
#pragma unroll
  for (int i = 0; i < 32; i += 8)
    h[((size_t)(n * CCH + c0 + ty + i)) * TLEN + t0 + tx] = tile[tx][ty + i];
}

// ---------------------------------------------------------------------------
// Pre-transpose shared conv weights [o][c][k] -> wT[i][k][c][o], and lin_W -> linWT[c][o]
__global__ __launch_bounds__(256) void k_prep_w(const float* __restrict__ w1,
                                                const float* __restrict__ w2,
                                                const float* __restrict__ linw,
                                                float* __restrict__ wT,
                                                float* __restrict__ linWT) {
  int idx = blockIdx.x * 256 + threadIdx.x;
  if (idx < 6 * 32768) {
    int o = idx & 127;
    int c = (idx >> 7) & 127;
    int k = (idx >> 14) & 1;
    int i = idx >> 15;
    const float* src = (i < 3) ? (w1 + i * 32768) : (w2 + (i - 3) * 32768);
    wT[idx] = src[(o * 128 + c) * 2 + k];
  }
  if (idx < 16384) {
    int o = idx & 127;
    int c = idx >> 7;
    linWT[idx] = linw[o * 128 + c];
  }
}

// ---------------------------------------------------------------------------
// gen = r @ fparam_W^T + fparam_b + last_bias, scattered directly into the
// transposed group-weight layout wg[i][m][k][c][o]  (flat reshape semantics:
// allw[i,m,o,c,k] = gen_flat[(((i*16+m)*128+o)*128+c)*2+k], gen_flat[n*GENL+g])
__global__ __launch_bounds__(256) void k_gen(const float* __restrict__ r,
                                             const float* __restrict__ fW,
                                             const float* __restrict__ fb,
                                             const float* __restrict__ lb,
                                             float* __restrict__ wg) {
  __shared__ float rl[NB][DR];  // 20 KB
  const int tid = threadIdx.x;
  for (int idx = tid; idx < NB * DR; idx += 256) ((float*)rl)[idx] = r[idx];
  __syncthreads();

  const int gbase = blockIdx.x * 1024 + tid;  // rows g = gbase + 256*j, j=0..3
  float acc[16][4];
#pragma unroll
  for (int n = 0; n < 16; n++)
#pragma unroll
    for (int j = 0; j < 4; j++) acc[n][j] = 0.f;

  const float4* w0 = (const float4*)(fW + (size_t)gbase * DR);
  for (int dq = 0; dq < DR / 4; dq++) {
    float4 w[4];
#pragma unroll
    for (int j = 0; j < 4; j++) w[j] = w0[(size_t)j * 256 * (DR / 4) + dq];
#pragma unroll
    for (int n = 0; n < 16; n++) {
      float4 rv = *(const float4*)&rl[n][dq * 4];
#pragma unroll
      for (int j = 0; j < 4; j++) {
        acc[n][j] += w[j].x * rv.x;
        acc[n][j] += w[j].y * rv.y;
        acc[n][j] += w[j].z * rv.z;
        acc[n][j] += w[j].w * rv.w;
      }
    }
  }

#pragma unroll
  for (int j = 0; j < 4; j++) {
    unsigned g = gbase + 256 * j;
    float add = fb[g] + lb[g];
#pragma unroll
    for (int n = 0; n < 16; n++) {
      unsigned f = (unsigned)n * GENL + g;
      unsigned k = f & 1u;
      unsigned c = (f >> 1) & 127u;
      unsigned o = (f >> 8) & 127u;
      unsigned m = (f >> 15) & 15u;
      unsigned i = f >> 19;
      wg[((((i * 16u + m) * 2u + k) * 128u + c) * 128u + o)] = acc[n][j] + add;
    }
  }
}

// ---------------------------------------------------------------------------
// Causal K=2 dilated conv, one (n, 64-t tile) per block, all 128 o.
// wBase layout [k][c][o] (perN: +n*32768). mode 0: out=relu(conv+b)
// mode 1: out=relu(relu(conv+b)+res)
template <int MAXD>
__global__ __launch_bounds__(256) void k_conv(const float* __restrict__ in,
                                              float* __restrict__ out,
                                              const float* __restrict__ res,
                                              const float* __restrict__ wBase,
                                              const float* __restrict__ bias,
                                              int d, int lgd, int perN, int mode) {
  __shared__ float hl[128][64 + MAXD + 1];
  __shared__ float wl[2][16][128];  // 16 KB

  const int tid = threadIdx.x;
  const int n = blockIdx.y;
  const int t0 = blockIdx.x * 64;
  const float* wT = wBase + (perN ? (size_t)n * 32768 : 0);
  const float* inN = in + (size_t)n * CCH * TLEN;

  // main tile: hl[c][d+x] = in[n][c][t0+x]
#pragma unroll
  for (int e = 0; e < 8192; e += 256) {
    int f = e + tid;
    int c = f >> 6, x = f & 63;
    hl[c][d + x] = inN[c * TLEN + t0 + x];
  }
  // left halo: hl[c][x] = in[n][c][t0-d+x] (0 if t<0); d is a power of two
  for (int f = tid; f < (128 << lgd); f += 256) {
    int c = f >> lgd, x = f & (d - 1);
    int t = t0 - d + x;
    hl[c][x] = (t >= 0) ? inN[c * TLEN + t] : 0.f;
  }

  const int tx = tid & 15, ty = tid >> 4;
  const int tl = tx * 4;   // 4 t per thread
  const int o0 = ty * 8;   // 8 o per thread

  float acc[8][4];
#pragma unroll
  for (int i = 0; i < 8; i++)
#pragma unroll
    for (int j = 0; j < 4; j++) acc[i][j] = 0.f;

  for (int c0 = 0; c0 < 128; c0 += 16) {
    __syncthreads();  // protects wl (and first time, hl staging)
#pragma unroll
    for (int e = 0; e < 4096; e += 256) {
      int f = e + tid;
      int k = f >> 11, cc = (f >> 7) & 15, o = f & 127;
      wl[k][cc][o] = wT[(k * 128 + c0 + cc) * 128 + o];
    }
    __syncthreads();
#pragma unroll
    for (int cc = 0; cc < 16; cc++) {
      int c = c0 + cc;
      float w0v[8], w1v[8], hd[4], hc[4];
#pragma unroll
      for (int i = 0; i < 8; i++) {
        w0v[i] = wl[0][cc][o0 + i];
        w1v[i] = wl[1][cc][o0 + i];
      }
#pragma unroll
      for (int j = 0; j < 4; j++) {
        hd[j] = hl[c][tl + j];      // x[t-d]
        hc[j] = hl[c][d + tl + j];  // x[t]
      }
#pragma unroll
      for (int i = 0; i < 8; i++)
#pragma unroll
        for (int j = 0; j < 4; j++)
          acc[i][j] += w0v[i] * hd[j] + w1v[i] * hc[j];
    }
  }

  float* outN = out + (size_t)n * CCH * TLEN;
  const float* resN = res ? res + (size_t)n * CCH * TLEN : nullptr;
#pragma unroll
  for (int i = 0; i < 8; i++) {
    int o = o0 + i;
    float b = bias ? bias[o] : 0.f;
    float z[4];
#pragma unroll
    for (int j = 0; j < 4; j++) z[j] = fmaxf(acc[i][j] + b, 0.f);
    int off = o * TLEN + t0 + tl;
    if (mode == 1) {
      float4 rv = *(const float4*)(resN + off);
      z[0] = fmaxf(z[0] + rv.x, 0.f);
      z[1] = fmaxf(z[1] + rv.y, 0.f);
      z[2] = fmaxf(z[2] + rv.z, 0.f);
      z[3] = fmaxf(z[3] + rv.w, 0.f);
    }
    float4 v = make_float4(z[0], z[1], z[2], z[3]);
    *(float4*)(outN + off) = v;
  }
}

// ---------------------------------------------------------------------------
// Final linear: out[n][t][o] = sum_c h[n][c][t] * linWT[c][o] + lin_b[o]
__global__ __launch_bounds__(256) void k_linear(const float* __restrict__ in,
                                                float* __restrict__ out,
                                                const float* __restrict__ wT,
                                                const float* __restrict__ b) {
  __shared__ float hlt[128][64];  // 32 KB
  __shared__ float wl[32][128];   // 16 KB
  const int tid = threadIdx.x;
  const int n = blockIdx.y, t0 = blockIdx.x * 64;
  const float* inN = in + (size_t)n * CCH * TLEN;
#pragma unroll
  for (int e = 0; e < 8192; e += 256) {
    int f = e + tid;
    int c = f >> 6, x = f & 63;
    hlt[c][x] = inN[c * TLEN + t0 + x];
  }
  const int ox = tid & 31, tz = tid >> 5;
  const int o0 = ox * 4, tl = tz * 8;
  float acc[8][4];
#pragma unroll
  for (int j = 0; j < 8; j++)
#pragma unroll
    for (int q = 0; q < 4; q++) acc[j][q] = 0.f;

  for (int c0 = 0; c0 < 128; c0 += 32) {
    __syncthreads();
#pragma unroll
    for (int e = 0; e < 4096; e += 256) {
      int f = e + tid;
      int cc = f >> 7, o = f & 127;
      wl[cc][o] = wT[(c0 + cc) * 128 + o];
    }
    __syncthreads();
#pragma unroll
    for (int cc = 0; cc < 32; cc++) {
      int c = c0 + cc;
      float4 wv = *(const float4*)&wl[cc][o0];
      float hv[8];
#pragma unroll
      for (int j = 0; j < 8; j++) hv[j] = hlt[c][tl + j];
#pragma unroll
      for (int j = 0; j < 8; j++) {
        acc[j][0] += hv[j] * wv.x;
        acc[j][1] += hv[j] * wv.y;
        acc[j][2] += hv[j] * wv.z;
        acc[j][3] += hv[j] * wv.w;
      }
    }
  }
  float4 bv = *(const float4*)(b + o0);
#pragma unroll
  for (int j = 0; j < 8; j++) {
    int t = t0 + tl + j;
    float4 v = make_float4(acc[j][0] + bv.x, acc[j][1] + bv.y,
                           acc[j][2] + bv.z, acc[j][3] + bv.w);
    *(float4*)(out + ((size_t)n * TLEN + t) * CCH + o0) = v;
  }
}

// ---------------------------------------------------------------------------
extern "C" void kernel_launch(void* const* d_in, const int* in_sizes, int n_in,
                              void* d_out, int out_size, void* d_ws, size_t ws_size,
                              hipStream_t stream) {
  const float* x  = (const float*)d_in[0];
  const float* r  = (const float*)d_in[1];
  // d_in[2] = f_out_same_in_size (==1, full output)
  const float* w1 = (const float*)d_in[3];
  const float* b1 = (const float*)d_in[4];
  const float* w2 = (const float*)d_in[5];
  const float* b2 = (const float*)d_in[6];
  const float* fW = (const float*)d_in[7];
  const float* fb = (const float*)d_in[8];
  const float* lb = (const float*)d_in[9];
  const float* lw = (const float*)d_in[10];
  const float* lbias = (const float*)d_in[11];
  float* out = (float*)d_out;

  float* buf0  = (float*)d_ws;            // 2097152 floats
  float* buf1  = buf0 + 2097152;          // 2097152
  float* wT    = buf1 + 2097152;          // 6*32768 = 196608
  float* linWT = wT + 196608;             // 16384
  float* wg    = linWT + 16384;           // 3*16*32768 = 1572864
  // total 5980160 floats = 23.9 MB

  k_transpose<<<dim3(32, 4, 16), dim3(32, 8, 1), 0, stream>>>(x, buf0);
  k_prep_w<<<768, 256, 0, stream>>>(w1, w2, lw, wT, linWT);
  k_gen<<<96, 256, 0, stream>>>(r, fW, fb, lb, wg);

  for (int i = 0; i < 3; i++) {
    k_conv<4><<<dim3(16, 16), 256, 0, stream>>>(buf0, buf1, nullptr,
                                                wT + i * 32768, b1 + i * 128,
                                                1 << i, i, 0, 0);
    k_conv<4><<<dim3(16, 16), 256, 0, stream>>>(buf1, buf0, buf0,
                                                wT + (3 + i) * 32768, b2 + i * 128,
                                                1 << i, i, 0, 1);
  }

  float* cur = buf0;
  float* alt = buf1;
  for (int i = 0; i < 3; i++) {
    k_conv<32><<<dim3(16, 16), 256, 0, stream>>>(cur, alt, cur,
                                                 wg + (size_t)i * 524288, nullptr,
                                                 8 << i, 3 + i, 1, 1);
    float* tmp = cur; cur = alt; alt = tmp;
  }

  k_linear<<<dim3(16, 16), 256, 0, stream>>>(cur, out, linWT, lbias);
}

// Round 2
// 382.198 us; speedup vs baseline: 1.8604x; 1.8604x over previous
//
#include <hip/hip_runtime.h>

// Problem constants
#define NB    16
#define TLEN  1024
#define CCH   128      // channels
#define DR    320
#define GENL  98304    // 3*128*128*2

// ---------------------------------------------------------------------------
// Transpose x (N,T,C) -> h (N,C,T)
__global__ __launch_bounds__(256) void k_transpose(const float* __restrict__ x,
                                                   float* __restrict__ h) {
  __shared__ float tile[32][33];
  const int n  = blockIdx.z;
  const int t0 = blockIdx.x * 32;
  const int c0 = blockIdx.y * 32;
  const int tx = threadIdx.x, ty = threadIdx.y;
#pragma unroll
  for (int i = 0; i < 32; i += 8)
    tile[ty + i][tx] = x[((size_t)(n * TLEN + t0 + ty + i)) * CCH + c0 + tx];
  __syncthreads();
#pragma unroll
  for (int i = 0; i < 32; i += 8)
    h[((size_t)(n * CCH + c0 + ty + i)) * TLEN + t0 + tx] = tile[tx][ty + i];
}

// ---------------------------------------------------------------------------
// Pre-transpose shared conv weights [o][c][k] -> wT[i][k][c][o], lin_W -> linWT[c][o]
__global__ __launch_bounds__(256) void k_prep_w(const float* __restrict__ w1,
                                                const float* __restrict__ w2,
                                                const float* __restrict__ linw,
                                                float* __restrict__ wT,
                                                float* __restrict__ linWT) {
  int idx = blockIdx.x * 256 + threadIdx.x;
  if (idx < 6 * 32768) {
    int o = idx & 127;
    int c = (idx >> 7) & 127;
    int k = (idx >> 14) & 1;
    int i = idx >> 15;
    const float* src = (i < 3) ? (w1 + i * 32768) : (w2 + (i - 3) * 32768);
    wT[idx] = src[(o * 128 + c) * 2 + k];
  }
  if (idx < 16384) {
    int o = idx & 127;
    int c = idx >> 7;
    linWT[idx] = linw[o * 128 + c];
  }
}

// ---------------------------------------------------------------------------
// gen = r @ fparam_W^T + fparam_b + last_bias, scattered into wg[i][m][k][c][o].
// 8 lanes per row (coalesced 128 B per octet), 4 rows per lane-group,
// 128 rows per 256-thread block -> 768 blocks.
__global__ __launch_bounds__(256) void k_gen(const float* __restrict__ r,
                                             const float* __restrict__ fW,
                                             const float* __restrict__ fb,
                                             const float* __restrict__ lb,
                                             float* __restrict__ wg) {
  __shared__ float rl[NB * DR];  // 20 KB
  const int tid = threadIdx.x;
  for (int f = tid; f < NB * DR / 4; f += 256)
    ((float4*)rl)[f] = ((const float4*)r)[f];
  __syncthreads();

  const int l = tid & 7;                         // lane within row-group
  const int g0 = blockIdx.x * 128 + (tid >> 3) * 4;  // 4 consecutive rows

  float acc[4][16];
#pragma unroll
  for (int i = 0; i < 4; i++)
#pragma unroll
    for (int n = 0; n < 16; n++) acc[i][n] = 0.f;

  const float* w0 = fW + (size_t)g0 * DR + l * 4;
#pragma unroll 2
  for (int s = 0; s < 10; s++) {
    float4 w[4];
#pragma unroll
    for (int i = 0; i < 4; i++)
      w[i] = *(const float4*)(w0 + i * DR + s * 32);
#pragma unroll
    for (int n = 0; n < 16; n++) {
      float4 rv = *(const float4*)&rl[n * DR + l * 4 + s * 32];
#pragma unroll
      for (int i = 0; i < 4; i++) {
        acc[i][n] += w[i].x * rv.x;
        acc[i][n] += w[i].y * rv.y;
        acc[i][n] += w[i].z * rv.z;
        acc[i][n] += w[i].w * rv.w;
      }
    }
  }

  // reduce across the 8 lanes of the group
#pragma unroll
  for (int m = 1; m <= 4; m <<= 1)
#pragma unroll
    for (int i = 0; i < 4; i++)
#pragma unroll
      for (int n = 0; n < 16; n++)
        acc[i][n] += __shfl_xor(acc[i][n], m, 64);

  // lane l writes batches n = 2l, 2l+1 for its 4 rows
#pragma unroll
  for (int i = 0; i < 4; i++) {
    unsigned g = g0 + i;
    float add = fb[g] + lb[g];
#pragma unroll
    for (int jj = 0; jj < 2; jj++) {
      unsigned n = (unsigned)l * 2 + jj;
      unsigned f = n * (unsigned)GENL + g;
      unsigned k = f & 1u;
      unsigned c = (f >> 1) & 127u;
      unsigned o = (f >> 8) & 127u;
      unsigned m2 = (f >> 15) & 15u;
      unsigned ii = f >> 19;
      wg[((((ii * 16u + m2) * 2u + k) * 128u + c) * 128u + o)] = acc[i][n] + add;
    }
  }
}

// ---------------------------------------------------------------------------
// Causal K=2 dilated conv. Block = 128 o x 32 t for one n; grid (32, 16).
// Per-thread tile 4o x 4t. All inner LDS reads are b128 (8-way broadcast).
// wBase layout [k][c][o] (+ n*wStrideN). mode 0: out=relu(conv+b);
// mode 1: out=relu(relu(conv+b)+res)
template <int D>
__global__ __launch_bounds__(256) void k_conv(const float* __restrict__ in,
                                              float* __restrict__ out,
                                              const float* __restrict__ res,
                                              const float* __restrict__ wBase,
                                              size_t wStrideN,
                                              const float* __restrict__ bias,
                                              int mode) {
  constexpr int S = D + 36;            // LDS row stride (floats), %4==0
  __shared__ float hl[128 * S];        // <= 34.8 KB (D=32)
  __shared__ float wl[2][16][128];     // 16 KB

  const int tid = threadIdx.x;
  const int n = blockIdx.y;
  const int t0 = blockIdx.x * 32;
  const float* wT = wBase + (size_t)n * wStrideN;
  const float* inN = in + (size_t)n * (CCH * TLEN);

  // stage hl: hl[c][p] = h[c][t0 - D + p]
  if constexpr (D >= 4) {
    constexpr int NQ = (D + 32) / 4;   // exact for D%4==0; =9 for D==4
    for (int f = tid; f < 128 * NQ; f += 256) {
      int c = f / NQ, q = f - c * NQ;
      int t = t0 - D + q * 4;
      float4 v = make_float4(0.f, 0.f, 0.f, 0.f);
      if (t >= 0) v = *(const float4*)(inN + c * TLEN + t);
      *(float4*)(&hl[c * S + q * 4]) = v;
    }
  } else {
    // main region p = D..D+31, aligned loads at t0+4q
    for (int f = tid; f < 128 * 8; f += 256) {
      int c = f >> 3, q = f & 7;
      *(float4*)(&hl[c * S + D + q * 4]) =
          *(const float4*)(inN + c * TLEN + t0 + q * 4);
    }
    // halo p = 0..D-1 (scalar)
    for (int f = tid; f < 128 * D; f += 256) {
      int c = f / D, j = f - c * D;
      int t = t0 - D + j;
      hl[c * S + j] = (t >= 0) ? inN[c * TLEN + t] : 0.f;
    }
  }

  const int tx = tid & 7, ty = tid >> 3;  // tx: t-group, ty: o-group
  const int tl = tx * 4;
  const int o0 = ty * 4;

  float acc[4][4];
#pragma unroll
  for (int i = 0; i < 4; i++)
#pragma unroll
    for (int j = 0; j < 4; j++) acc[i][j] = 0.f;

  for (int c0 = 0; c0 < 128; c0 += 16) {
    __syncthreads();
    // stage wl[2][16][128] = 1024 float4
    for (int f = tid; f < 1024; f += 256) {
      int k = f >> 9, cc = (f >> 5) & 15, oq = f & 31;
      ((float4*)wl)[f] =
          *(const float4*)(wT + ((size_t)(k * 128 + c0 + cc)) * 128 + oq * 4);
    }
    __syncthreads();
#pragma unroll
    for (int cc = 0; cc < 16; cc++) {
      float4 w0 = *(const float4*)&wl[0][cc][o0];
      float4 w1 = *(const float4*)&wl[1][cc][o0];
      const float* hr = &hl[(c0 + cc) * S];
      float4 hdv = *(const float4*)(hr + tl);
      float4 hcv;
      if constexpr (D == 1) {
        float4 hn = *(const float4*)(hr + tl + 4);
        hcv = make_float4(hdv.y, hdv.z, hdv.w, hn.x);
      } else if constexpr (D == 2) {
        float4 hn = *(const float4*)(hr + tl + 4);
        hcv = make_float4(hdv.z, hdv.w, hn.x, hn.y);
      } else {
        hcv = *(const float4*)(hr + tl + D);
      }
      const float wa[4] = {w0.x, w0.y, w0.z, w0.w};
      const float wb[4] = {w1.x, w1.y, w1.z, w1.w};
      const float hd[4] = {hdv.x, hdv.y, hdv.z, hdv.w};
      const float hc[4] = {hcv.x, hcv.y, hcv.z, hcv.w};
#pragma unroll
      for (int i = 0; i < 4; i++)
#pragma unroll
        for (int j = 0; j < 4; j++)
          acc[i][j] += wa[i] * hd[j] + wb[i] * hc[j];
    }
  }

  float* outN = out + (size_t)n * (CCH * TLEN);
  const float* resN = res ? res + (size_t)n * (CCH * TLEN) : nullptr;
#pragma unroll
  for (int i = 0; i < 4; i++) {
    int o = o0 + i;
    float b = bias ? bias[o] : 0.f;
    float z[4];
#pragma unroll
    for (int j = 0; j < 4; j++) z[j] = fmaxf(acc[i][j] + b, 0.f);
    int off = o * TLEN + t0 + tl;
    if (mode == 1) {
      float4 rv = *(const float4*)(resN + off);
      z[0] = fmaxf(z[0] + rv.x, 0.f);
      z[1] = fmaxf(z[1] + rv.y, 0.f);
      z[2] = fmaxf(z[2] + rv.z, 0.f);
      z[3] = fmaxf(z[3] + rv.w, 0.f);
    }
    *(float4*)(outN + off) = make_float4(z[0], z[1], z[2], z[3]);
  }
}

// ---------------------------------------------------------------------------
// Final linear: out[n][t][o] = sum_c h[n][c][t] * linWT[c][o] + lin_b[o]
// Block = 128 o x 32 t; grid (32,16); per-thread 4o x 4t.
__global__ __launch_bounds__(256) void k_linear(const float* __restrict__ in,
                                                float* __restrict__ out,
                                                const float* __restrict__ wT,
                                                const float* __restrict__ b) {
  __shared__ float hlt[128][32];  // 16 KB
  __shared__ float wl[32][128];   // 16 KB
  const int tid = threadIdx.x;
  const int n = blockIdx.y, t0 = blockIdx.x * 32;
  const float* inN = in + (size_t)n * (CCH * TLEN);
  for (int f = tid; f < 128 * 8; f += 256) {
    int c = f >> 3, q = f & 7;
    *(float4*)(&hlt[c][q * 4]) = *(const float4*)(inN + c * TLEN + t0 + q * 4);
  }

  const int tx = tid & 7, ty = tid >> 3;
  const int tl = tx * 4, o0 = ty * 4;
  float acc[4][4];
#pragma unroll
  for (int i = 0; i < 4; i++)
#pragma unroll
    for (int j = 0; j < 4; j++) acc[i][j] = 0.f;

  for (int c0 = 0; c0 < 128; c0 += 32) {
    __syncthreads();
    for (int f = tid; f < 1024; f += 256) {
      int cc = f >> 5, oq = f & 31;
      *(float4*)(&wl[cc][oq * 4]) =
          *(const float4*)(wT + (size_t)(c0 + cc) * 128 + oq * 4);
    }
    __syncthreads();
#pragma unroll
    for (int cc = 0; cc < 32; cc++) {
      float4 wv = *(const float4*)&wl[cc][o0];
      float4 hv = *(const float4*)&hlt[c0 + cc][tl];
      const float wa[4] = {wv.x, wv.y, wv.z, wv.w};
      const float ha[4] = {hv.x, hv.y, hv.z, hv.w};
#pragma unroll
      for (int i = 0; i < 4; i++)
#pragma unroll
        for (int j = 0; j < 4; j++) acc[i][j] += ha[j] * wa[i];
    }
  }
  float4 bv = *(const float4*)(b + o0);
#pragma unroll
  for (int j = 0; j < 4; j++) {
    int t = t0 + tl + j;
    float4 v = make_float4(acc[0][j] + bv.x, acc[1][j] + bv.y,
                           acc[2][j] + bv.z, acc[3][j] + bv.w);
    *(float4*)(out + ((size_t)n * TLEN + t) * CCH + o0) = v;
  }
}

// ---------------------------------------------------------------------------
extern "C" void kernel_launch(void* const* d_in, const int* in_sizes, int n_in,
                              void* d_out, int out_size, void* d_ws, size_t ws_size,
                              hipStream_t stream) {
  const float* x  = (const float*)d_in[0];
  const float* r  = (const float*)d_in[1];
  // d_in[2] = f_out_same_in_size (==1, full output)
  const float* w1 = (const float*)d_in[3];
  const float* b1 = (const float*)d_in[4];
  const float* w2 = (const float*)d_in[5];
  const float* b2 = (const float*)d_in[6];
  const float* fW = (const float*)d_in[7];
  const float* fb = (const float*)d_in[8];
  const float* lb = (const float*)d_in[9];
  const float* lw = (const float*)d_in[10];
  const float* lbias = (const float*)d_in[11];
  float* out = (float*)d_out;

  float* buf0  = (float*)d_ws;            // 2097152 floats
  float* buf1  = buf0 + 2097152;          // 2097152
  float* wT    = buf1 + 2097152;          // 6*32768 = 196608
  float* linWT = wT + 196608;             // 16384
  float* wg    = linWT + 16384;           // 3*16*32768 = 1572864

  k_transpose<<<dim3(32, 4, 16), dim3(32, 8, 1), 0, stream>>>(x, buf0);
  k_prep_w<<<768, 256, 0, stream>>>(w1, w2, lw, wT, linWT);
  k_gen<<<768, 256, 0, stream>>>(r, fW, fb, lb, wg);

  const dim3 cgrid(32, 16);
  // shared blocks
  k_conv<1><<<cgrid, 256, 0, stream>>>(buf0, buf1, nullptr, wT + 0 * 32768, 0, b1 + 0 * 128, 0);
  k_conv<1><<<cgrid, 256, 0, stream>>>(buf1, buf0, buf0,    wT + 3 * 32768, 0, b2 + 0 * 128, 1);
  k_conv<2><<<cgrid, 256, 0, stream>>>(buf0, buf1, nullptr, wT + 1 * 32768, 0, b1 + 1 * 128, 0);
  k_conv<2><<<cgrid, 256, 0, stream>>>(buf1, buf0, buf0,    wT + 4 * 32768, 0, b2 + 1 * 128, 1);
  k_conv<4><<<cgrid, 256, 0, stream>>>(buf0, buf1, nullptr, wT + 2 * 32768, 0, b1 + 2 * 128, 0);
  k_conv<4><<<cgrid, 256, 0, stream>>>(buf1, buf0, buf0,    wT + 5 * 32768, 0, b2 + 2 * 128, 1);
  // group blocks (per-n generated weights)
  k_conv<8> <<<cgrid, 256, 0, stream>>>(buf0, buf1, buf0, wg + 0 * 524288, 32768, nullptr, 1);
  k_conv<16><<<cgrid, 256, 0, stream>>>(buf1, buf0, buf1, wg + 1 * 524288, 32768, nullptr, 1);
  k_conv<32><<<cgrid, 256, 0, stream>>>(buf0, buf1, buf0, wg + 2 * 524288, 32768, nullptr, 1);

  k_linear<<<cgrid, 256, 0, stream>>>(buf1, out, linWT, lbias);
}

// Round 4
// 377.598 us; speedup vs baseline: 1.8831x; 1.0122x over previous
//
#include <hip/hip_runtime.h>

// Problem constants
#define NB    16
#define TLEN  1024
#define CCH   128      // channels
#define DR    320
#define GENL  98304    // 3*128*128*2

// async global -> LDS, 16 B per lane (requires linear lane->LDS mapping)
__device__ __forceinline__ void gload16(const float* g, float* l) {
  __builtin_amdgcn_global_load_lds(
      (const __attribute__((address_space(1))) void*)g,
      (__attribute__((address_space(3))) void*)l, 16, 0, 0);
}

// ---------------------------------------------------------------------------
// Transpose x (N,T,C) -> h (N,C,T)
__global__ __launch_bounds__(256) void k_transpose(const float* __restrict__ x,
                                                   float* __restrict__ h) {
  __shared__ float tile[32][33];
  const int n  = blockIdx.z;
  const int t0 = blockIdx.x * 32;
  const int c0 = blockIdx.y * 32;
  const int tx = threadIdx.x, ty = threadIdx.y;
#pragma unroll
  for (int i = 0; i < 32; i += 8)
    tile[ty + i][tx] = x[((size_t)(n * TLEN + t0 + ty + i)) * CCH + c0 + tx];
  __syncthreads();
#pragma unroll
  for (int i = 0; i < 32; i += 8)
    h[((size_t)(n * CCH + c0 + ty + i)) * TLEN + t0 + tx] = tile[tx][ty + i];
}

// ---------------------------------------------------------------------------
// wT[i][k][c][o], linWT[c][o], fblb[G][k][c][o] = fb[g]+lb[g], g=G*2^15+o*256+c*2+k
__global__ __launch_bounds__(256) void k_prep_w(const float* __restrict__ w1,
                                                const float* __restrict__ w2,
                                                const float* __restrict__ linw,
                                                const float* __restrict__ fb,
                                                const float* __restrict__ lb,
                                                float* __restrict__ wT,
                                                float* __restrict__ linWT,
                                                float* __restrict__ fblb) {
  int idx = blockIdx.x * 256 + threadIdx.x;
  if (idx < 6 * 32768) {
    int o = idx & 127;
    int c = (idx >> 7) & 127;
    int k = (idx >> 14) & 1;
    int i = idx >> 15;
    const float* src = (i < 3) ? (w1 + i * 32768) : (w2 + (i - 3) * 32768);
    wT[idx] = src[(o * 128 + c) * 2 + k];
  }
  if (idx < 16384) {
    int o = idx & 127;
    int c = idx >> 7;
    linWT[idx] = linw[o * 128 + c];
  }
  if (idx < GENL) {
    int g = idx;
    int G = g >> 15, o = (g >> 8) & 127, c = (g & 255) >> 1, k = g & 1;
    fblb[(((G * 2 + k) * 128) + c) * 128 + o] = fb[g] + lb[g];
  }
}

// ---------------------------------------------------------------------------
// gen GEMM, coalesced output. Block = (G,c,k), G = g>>15; computes columns
// g = G*2^15 + o*256 + c*2 + k for o=0..127, all 16 gen rows n.
// Element (row n, col g) belongs to allw flat q = 3n+G (= 16i+m), stored at
// wg[q][k][c][o] (which conv i, batch m reads at wg + (16i+m)*32768).
__global__ __launch_bounds__(256) void k_gen(const float* __restrict__ r,
                                             const float* __restrict__ fW,
                                             const float* __restrict__ fblb,
                                             float* __restrict__ wg) {
  __shared__ alignas(16) float rl[NB * DR];  // 20 KB
  const int tid = threadIdx.x;
  for (int f = tid; f < NB * DR / 4; f += 256)
    ((float4*)rl)[f] = ((const float4*)r)[f];
  __syncthreads();

  const int b = blockIdx.x;       // 768
  const int G = b >> 8;           // 0..2
  const int c = (b & 255) >> 1;
  const int k = b & 1;
  const int q8 = tid >> 3, l = tid & 7;
  const int o0 = q8 * 4;
  const size_t gbase = (size_t)G * 32768 + (size_t)c * 2 + k;

  float acc[4][16];
#pragma unroll
  for (int i2 = 0; i2 < 4; i2++)
#pragma unroll
    for (int n = 0; n < 16; n++) acc[i2][n] = 0.f;

  const float* w0 = fW + (gbase + (size_t)o0 * 256) * DR + l * 4;
#pragma unroll 2
  for (int s = 0; s < 10; s++) {
    float4 w[4];
#pragma unroll
    for (int i2 = 0; i2 < 4; i2++)
      w[i2] = *(const float4*)(w0 + (size_t)i2 * 256 * DR + s * 32);
#pragma unroll
    for (int n = 0; n < 16; n++) {
      float4 rv = *(const float4*)&rl[n * DR + l * 4 + s * 32];
#pragma unroll
      for (int i2 = 0; i2 < 4; i2++) {
        acc[i2][n] += w[i2].x * rv.x;
        acc[i2][n] += w[i2].y * rv.y;
        acc[i2][n] += w[i2].z * rv.z;
        acc[i2][n] += w[i2].w * rv.w;
      }
    }
  }

#pragma unroll
  for (int m = 1; m <= 4; m <<= 1)
#pragma unroll
    for (int i2 = 0; i2 < 4; i2++)
#pragma unroll
      for (int n = 0; n < 16; n++)
        acc[i2][n] += __shfl_xor(acc[i2][n], m, 64);

  float4 bv = *(const float4*)&fblb[(((size_t)G * 2 + k) * 128 + c) * 128 + o0];
#pragma unroll
  for (int jj = 0; jj < 2; jj++) {
    int n = l * 2 + jj;
    int q = 3 * n + G;  // = 16i+m in allw space
    float4 v = make_float4(acc[0][n] + bv.x, acc[1][n] + bv.y,
                           acc[2][n] + bv.z, acc[3][n] + bv.w);
    *(float4*)&wg[(((size_t)q * 2 + k) * 128 + c) * 128 + o0] = v;
  }
}

// ---------------------------------------------------------------------------
// Causal K=2 dilated conv. Block = 128 o x 64 t, 256 threads, grid (16,16).
// Per-thread 8o x 4t. Double-buffered 32-c weight chunks, async staging,
// one barrier per chunk. wBase layout [k][c][o] (+ n*wStrideN).
// mode 0: out=relu(conv+b);  mode 1: out=relu(relu(conv+b)+res)
template <int D>
__global__ __launch_bounds__(256) void k_conv(const float* __restrict__ in,
                                              float* __restrict__ out,
                                              const float* __restrict__ res,
                                              const float* __restrict__ wBase,
                                              size_t wStrideN,
                                              const float* __restrict__ bias,
                                              int mode) {
  constexpr int H = (D < 8) ? 8 : D;   // staged halo (keeps NQ even)
  constexpr int S = H + 64;            // LDS row stride (floats)
  constexpr int NQ = S / 4;            // float4 per row (even)
  __shared__ alignas(16) float hl[128 * S];        // <= 49,152 B (D=32)
  __shared__ alignas(16) float wl[2][2][32][128];  // 64 KB

  const int tid = threadIdx.x;
  const int n = blockIdx.y;
  const int t0 = blockIdx.x * 64;
  const float* wT = wBase + (size_t)n * wStrideN;
  const float* inN = in + (size_t)n * (CCH * TLEN);

  // stage h: hl[c][p] = h[c][t0 - H + p]
  if (blockIdx.x != 0) {
    const float* src = inN + t0 - H;
    for (int f = tid; f < 128 * NQ; f += 256) {
      int c = f / NQ, qq = f - c * NQ;
      gload16(src + c * TLEN + qq * 4, &hl[f * 4]);
    }
  } else {
    for (int f = tid; f < 128 * NQ; f += 256) {
      int c = f / NQ, qq = f - c * NQ;
      int t = qq * 4 - H;
      float4 v = make_float4(0.f, 0.f, 0.f, 0.f);
      if (t >= 0) v = *(const float4*)(inN + c * TLEN + t);
      *(float4*)&hl[f * 4] = v;
    }
  }
  // stage weight chunk 0 (c = 0..31)
  for (int f = tid; f < 2048; f += 256) {
    int k = f >> 10, cc = (f >> 5) & 31, oq = f & 31;
    gload16(wT + (size_t)((k * 128 + cc) * 128 + oq * 4), (float*)wl + f * 4);
  }
  __syncthreads();

  const int tx = tid & 15, oy = tid >> 4;
  const int tl = tx * 4;
  const int o0 = oy * 8;

  float acc[8][4] = {};

  for (int ch = 0; ch < 4; ch++) {
    const float(*wb)[32][128] = wl[ch & 1];
    if (ch < 3) {
      float* dst = (float*)wl[(ch & 1) ^ 1];
      int c0n = (ch + 1) * 32;
      for (int f = tid; f < 2048; f += 256) {
        int k = f >> 10, cc = (f >> 5) & 31, oq = f & 31;
        gload16(wT + (size_t)((k * 128 + c0n + cc) * 128 + oq * 4), dst + f * 4);
      }
    }
#pragma unroll
    for (int cc = 0; cc < 32; cc++) {
      int c = ch * 32 + cc;
      const float* hr = &hl[c * S];
      float4 w0a = *(const float4*)&wb[0][cc][o0];
      float4 w0b = *(const float4*)&wb[0][cc][o0 + 4];
      float4 w1a = *(const float4*)&wb[1][cc][o0];
      float4 w1b = *(const float4*)&wb[1][cc][o0 + 4];
      float4 hcv = *(const float4*)(hr + tl + H);  // x[t]
      float4 hdv;                                  // x[t-D]
      if constexpr (D >= 4) {
        hdv = *(const float4*)(hr + tl + (H - D));
      } else {
        float4 hp = *(const float4*)(hr + tl + 4);
        if constexpr (D == 1)
          hdv = make_float4(hp.w, hcv.x, hcv.y, hcv.z);
        else
          hdv = make_float4(hp.z, hp.w, hcv.x, hcv.y);
      }
      const float wa[8] = {w0a.x, w0a.y, w0a.z, w0a.w, w0b.x, w0b.y, w0b.z, w0b.w};
      const float wc[8] = {w1a.x, w1a.y, w1a.z, w1a.w, w1b.x, w1b.y, w1b.z, w1b.w};
      const float hd[4] = {hdv.x, hdv.y, hdv.z, hdv.w};
      const float hc[4] = {hcv.x, hcv.y, hcv.z, hcv.w};
#pragma unroll
      for (int i = 0; i < 8; i++)
#pragma unroll
        for (int j = 0; j < 4; j++)
          acc[i][j] += wa[i] * hd[j] + wc[i] * hc[j];
    }
    __syncthreads();
  }

  float* outN = out + (size_t)n * (CCH * TLEN);
  const float* resN = res ? res + (size_t)n * (CCH * TLEN) : nullptr;
#pragma unroll
  for (int i = 0; i < 8; i++) {
    int o = o0 + i;
    float b = bias ? bias[o] : 0.f;
    float z[4];
#pragma unroll
    for (int j = 0; j < 4; j++) z[j] = fmaxf(acc[i][j] + b, 0.f);
    int off = o * TLEN + t0 + tl;
    if (mode == 1) {
      float4 rv = *(const float4*)(resN + off);
      z[0] = fmaxf(z[0] + rv.x, 0.f);
      z[1] = fmaxf(z[1] + rv.y, 0.f);
      z[2] = fmaxf(z[2] + rv.z, 0.f);
      z[3] = fmaxf(z[3] + rv.w, 0.f);
    }
    *(float4*)(outN + off) = make_float4(z[0], z[1], z[2], z[3]);
  }
}

// ---------------------------------------------------------------------------
// Final linear: out[n][t][o] = sum_c h[n][c][t] * linWT[c][o] + lin_b[o]
// Block = 128 o x 64 t, 256 threads, grid (16,16); per-thread 8o x 4t.
__global__ __launch_bounds__(256) void k_linear(const float* __restrict__ in,
                                                float* __restrict__ out,
                                                const float* __restrict__ wT,
                                                const float* __restrict__ b) {
  __shared__ alignas(16) float hlt[128 * 64];      // 32 KB
  __shared__ alignas(16) float wl[2][32][128];     // 32 KB
  const int tid = threadIdx.x;
  const int n = blockIdx.y, t0 = blockIdx.x * 64;
  const float* inN = in + (size_t)n * (CCH * TLEN);

  for (int f = tid; f < 128 * 16; f += 256)
    gload16(inN + (f >> 4) * TLEN + t0 + (f & 15) * 4, &hlt[f * 4]);
  for (int f = tid; f < 1024; f += 256)
    gload16(wT + (size_t)((f >> 5) * 128 + (f & 31) * 4), (float*)wl + f * 4);
  __syncthreads();

  const int tx = tid & 15, oy = tid >> 4;
  const int tl = tx * 4, o0 = oy * 8;
  float acc[8][4] = {};

  for (int ch = 0; ch < 4; ch++) {
    const float(*wb)[128] = wl[ch & 1];
    if (ch < 3) {
      float* dst = (float*)wl[(ch & 1) ^ 1];
      int c0n = (ch + 1) * 32;
      for (int f = tid; f < 1024; f += 256)
        gload16(wT + (size_t)((c0n + (f >> 5)) * 128 + (f & 31) * 4), dst + f * 4);
    }
#pragma unroll
    for (int cc = 0; cc < 32; cc++) {
      int c = ch * 32 + cc;
      float4 wva = *(const float4*)&wb[cc][o0];
      float4 wvb = *(const float4*)&wb[cc][o0 + 4];
      float4 hv = *(const float4*)&hlt[c * 64 + tl];
      const float wa[8] = {wva.x, wva.y, wva.z, wva.w, wvb.x, wvb.y, wvb.z, wvb.w};
      const float ha[4] = {hv.x, hv.y, hv.z, hv.w};
#pragma unroll
      for (int i = 0; i < 8; i++)
#pragma unroll
        for (int j = 0; j < 4; j++) acc[i][j] += ha[j] * wa[i];
    }
    __syncthreads();
  }

  float4 bva = *(const float4*)(b + o0);
  float4 bvb = *(const float4*)(b + o0 + 4);
#pragma unroll
  for (int j = 0; j < 4; j++) {
    int t = t0 + tl + j;
    float* op = out + ((size_t)n * TLEN + t) * CCH + o0;
    *(float4*)op = make_float4(acc[0][j] + bva.x, acc[1][j] + bva.y,
                               acc[2][j] + bva.z, acc[3][j] + bva.w);
    *(float4*)(op + 4) = make_float4(acc[4][j] + bvb.x, acc[5][j] + bvb.y,
                                     acc[6][j] + bvb.z, acc[7][j] + bvb.w);
  }
}

// ---------------------------------------------------------------------------
extern "C" void kernel_launch(void* const* d_in, const int* in_sizes, int n_in,
                              void* d_out, int out_size, void* d_ws, size_t ws_size,
                              hipStream_t stream) {
  const float* x  = (const float*)d_in[0];
  const float* r  = (const float*)d_in[1];
  // d_in[2] = f_out_same_in_size (==1, full output)
  const float* w1 = (const float*)d_in[3];
  const float* b1 = (const float*)d_in[4];
  const float* w2 = (const float*)d_in[5];
  const float* b2 = (const float*)d_in[6];
  const float* fW = (const float*)d_in[7];
  const float* fb = (const float*)d_in[8];
  const float* lb = (const float*)d_in[9];
  const float* lw = (const float*)d_in[10];
  const float* lbias = (const float*)d_in[11];
  float* out = (float*)d_out;

  float* buf0  = (float*)d_ws;            // 2097152 floats
  float* buf1  = buf0 + 2097152;          // 2097152
  float* wT    = buf1 + 2097152;          // 196608
  float* linWT = wT + 196608;             // 16384
  float* wg    = linWT + 16384;           // 1572864
  float* fblb  = wg + 1572864;            // 98304   (total 24.3 MB)

  k_transpose<<<dim3(32, 4, 16), dim3(32, 8, 1), 0, stream>>>(x, buf0);
  k_prep_w<<<768, 256, 0, stream>>>(w1, w2, lw, fb, lb, wT, linWT, fblb);
  k_gen<<<768, 256, 0, stream>>>(r, fW, fblb, wg);

  const dim3 cgrid(16, 16);
  // shared blocks
  k_conv<1><<<cgrid, 256, 0, stream>>>(buf0, buf1, nullptr, wT + 0 * 32768, 0, b1 + 0 * 128, 0);
  k_conv<1><<<cgrid, 256, 0, stream>>>(buf1, buf0, buf0,    wT + 3 * 32768, 0, b2 + 0 * 128, 1);
  k_conv<2><<<cgrid, 256, 0, stream>>>(buf0, buf1, nullptr, wT + 1 * 32768, 0, b1 + 1 * 128, 0);
  k_conv<2><<<cgrid, 256, 0, stream>>>(buf1, buf0, buf0,    wT + 4 * 32768, 0, b2 + 1 * 128, 1);
  k_conv<4><<<cgrid, 256, 0, stream>>>(buf0, buf1, nullptr, wT + 2 * 32768, 0, b1 + 2 * 128, 0);
  k_conv<4><<<cgrid, 256, 0, stream>>>(buf1, buf0, buf0,    wT + 5 * 32768, 0, b2 + 2 * 128, 1);
  // group blocks (per-n generated weights): conv i, batch n -> wg + (16i+n)*32768
  k_conv<8> <<<cgrid, 256, 0, stream>>>(buf0, buf1, buf0, wg + 0 * 524288, 32768, nullptr, 1);
  k_conv<16><<<cgrid, 256, 0, stream>>>(buf1, buf0, buf1, wg + 1 * 524288, 32768, nullptr, 1);
  k_conv<32><<<cgrid, 256, 0, stream>>>(buf0, buf1, buf0, wg + 2 * 524288, 32768, nullptr, 1);

  k_linear<<<cgrid, 256, 0, stream>>>(buf1, out, linWT, lbias);
}

// Round 5
// 131.937 us; speedup vs baseline: 5.3893x; 2.8619x over previous
//
#include <hip/hip_runtime.h>

// Problem constants
#define NB    16
#define TLEN  1024
#define CCH   128
#define DR    320
#define GENL  98304    // 3*128*128*2

typedef _Float16 h8 __attribute__((ext_vector_type(8)));
typedef _Float16 h4 __attribute__((ext_vector_type(4)));
typedef float    f4 __attribute__((ext_vector_type(4)));

// async global->LDS, 16 B/lane (linear lane->LDS mapping; swizzle goes on the
// GLOBAL source address, LDS dest stays linear — guide §5/m173 pattern)
__device__ __forceinline__ void gload16h(const _Float16* g, _Float16* l) {
  __builtin_amdgcn_global_load_lds(
      (const __attribute__((address_space(1))) void*)g,
      (__attribute__((address_space(3))) void*)l, 16, 0, 0);
}

// ---------------------------------------------------------------------------
// x (N,T,C) fp32 -> h0 (N,T,C) fp16  (pure cast; layout already t-major)
__global__ __launch_bounds__(256) void k_cast(const float* __restrict__ x,
                                              _Float16* __restrict__ h) {
  int i = blockIdx.x * 256 + threadIdx.x;     // 262144 threads, 8 elems each
  const float4* src = (const float4*)x + (size_t)i * 2;
  float4 a = src[0], b = src[1];
  h8 v;
  v[0] = (_Float16)a.x; v[1] = (_Float16)a.y; v[2] = (_Float16)a.z; v[3] = (_Float16)a.w;
  v[4] = (_Float16)b.x; v[5] = (_Float16)b.y; v[6] = (_Float16)b.z; v[7] = (_Float16)b.w;
  *(h8*)(h + (size_t)i * 8) = v;
}

// ---------------------------------------------------------------------------
// Shared conv weights [i][o][c][k] fp32 -> Wsh[i][o][k][c] fp16; lin_W -> fp16
__global__ __launch_bounds__(256) void k_prep_w(const float* __restrict__ w1,
                                                const float* __restrict__ w2,
                                                const float* __restrict__ linw,
                                                _Float16* __restrict__ Wsh,
                                                _Float16* __restrict__ linWh) {
  int idx = blockIdx.x * 256 + threadIdx.x;
  if (idx < 6 * 32768) {
    int c = idx & 127, k = (idx >> 7) & 1, o = (idx >> 8) & 127, i = idx >> 15;
    const float* src = (i < 3) ? (w1 + i * 32768) : (w2 + (i - 3) * 32768);
    Wsh[idx] = (_Float16)src[(o * 128 + c) * 2 + k];
  }
  if (idx < 16384) linWh[idx] = (_Float16)linw[idx];
}

// ---------------------------------------------------------------------------
// gen = r @ fparam_W^T + fb + lb -> Wg[q][o][k][c] fp16, q = 3n+G (= 16i+m).
// Block = (G, o, e): 32 fW rows (16 c x 2 k), one row per 8-lane octet.
// Octet streams its row (10 float4, all in flight), 3-level shfl_xor reduce.
__global__ __launch_bounds__(256) void k_genh(const float* __restrict__ r,
                                              const float* __restrict__ fW,
                                              const float* __restrict__ fb,
                                              const float* __restrict__ lb,
                                              _Float16* __restrict__ wg) {
  __shared__ alignas(16) float rl[NB * DR];  // 20 KB
  const int tid = threadIdx.x;
  for (int f = tid; f < NB * DR / 4; f += 256)
    ((float4*)rl)[f] = ((const float4*)r)[f];
  __syncthreads();

  const int b = blockIdx.x;           // ((G*8 + e)*128 + o) — o fastest so that
  const int o = b & 127;              // line-sharing blocks (same o) share XCD
  const int e = (b >> 7) & 7;
  const int G = b >> 10;
  const int j = tid >> 3, l = tid & 7;
  const int c = e * 16 + (j >> 1), k = j & 1;
  const unsigned g = G * 32768u + o * 256u + c * 2u + k;

  const float* wrow = fW + (size_t)g * DR + l * 4;
  float4 wv[10];
#pragma unroll
  for (int s = 0; s < 10; s++) wv[s] = *(const float4*)(wrow + s * 32);

  float acc[16] = {};
#pragma unroll
  for (int s = 0; s < 10; s++) {
#pragma unroll
    for (int n = 0; n < 16; n++) {
      float4 rv = *(const float4*)&rl[n * DR + l * 4 + s * 32];
      acc[n] += wv[s].x * rv.x + wv[s].y * rv.y + wv[s].z * rv.z + wv[s].w * rv.w;
    }
  }
#pragma unroll
  for (int m = 1; m <= 4; m <<= 1)
#pragma unroll
    for (int n = 0; n < 16; n++) acc[n] += __shfl_xor(acc[n], m, 64);

  const float add = fb[g] + lb[g];
#pragma unroll
  for (int jj = 0; jj < 2; jj++) {
    int n = l * 2 + jj;
    int q = 3 * n + G;
    wg[(((size_t)q * 128 + o) * 2 + k) * 128 + c] = (_Float16)(acc[n] + add);
  }
}

// ---------------------------------------------------------------------------
// MFMA causal K=2 dilated conv. h layout [n][t][c] fp16, W [o][tap][c] fp16.
// Block = one n, 64-t tile, 256 thr (4 waves, each 32 o x 64 t).
// GEMM: C[o,t] = sum_{tap,c} W[o][tap][c] * H[t - (1-tap)*D][c], K = tap*128+c.
// A and B fragments use the SAME (lane>>4, j)->k packing rule, so the HW
// k-permutation cancels. C/D: col=lane&15 (t), row=(lane>>4)*4+reg (o).
// LDS XOR-swizzle c ^ ((row&15)<<3); applied on the global source for staging.
template <int D>
__global__ __launch_bounds__(256) void k_mconv(const _Float16* __restrict__ in,
                                               _Float16* __restrict__ out,
                                               const _Float16* __restrict__ res,
                                               const _Float16* __restrict__ wBase,
                                               size_t wStrideN,
                                               const float* __restrict__ bias,
                                               int mode) {
  __shared__ _Float16 Wl[256 * 128];         // [o][tap][c] 64 KB
  __shared__ _Float16 hl[(64 + D) * 128];    // rows p: t = t0 - D + p
  const int tid = threadIdx.x;
  const int n = blockIdx.y, t0 = blockIdx.x * 64;
  const _Float16* inN = in + (size_t)n * (TLEN * CCH);
  const _Float16* wp = wBase + (size_t)n * wStrideN;

  // stage W: 256 rows (o*2+tap) x 16 chunks of 16 B, source pre-swizzled
  for (int f = tid; f < 4096; f += 256) {
    int row = f >> 4, l16 = f & 15;
    int c8 = (l16 ^ ((row >> 1) & 15)) << 3;
    gload16h(wp + row * 128 + c8, Wl + f * 8);
  }
  // stage h rows
  if (blockIdx.x == 0) {
    for (int f = tid; f < D * 16; f += 256)
      *(int4*)((char*)hl + (size_t)f * 16) = make_int4(0, 0, 0, 0);
    for (int f = D * 16 + tid; f < (64 + D) * 16; f += 256) {
      int p = f >> 4, l16 = f & 15;
      int c8 = (l16 ^ (p & 15)) << 3;
      gload16h(inN + (t0 - D + p) * 128 + c8, hl + f * 8);
    }
  } else {
    for (int f = tid; f < (64 + D) * 16; f += 256) {
      int p = f >> 4, l16 = f & 15;
      int c8 = (l16 ^ (p & 15)) << 3;
      gload16h(inN + (t0 - D + p) * 128 + c8, hl + f * 8);
    }
  }
  __syncthreads();

  const int l = tid & 63, w = tid >> 6;
  const int l15 = l & 15, lh = l >> 4;
  const int o0 = w * 32;
  f4 acc[2][4] = {};

#pragma unroll
  for (int tap = 0; tap < 2; tap++) {
#pragma unroll
    for (int cb = 0; cb < 4; cb++) {
      const int c0 = cb * 32 + 8 * lh;   // this lane's logical 8-c block
      h8 a[2], bfr[4];
#pragma unroll
      for (int i2 = 0; i2 < 2; i2++) {
        int o = o0 + i2 * 16 + l15;
        int cs = c0 ^ ((o & 15) << 3);
        a[i2] = *(const h8*)&Wl[(o * 2 + tap) * 128 + cs];
      }
#pragma unroll
      for (int jt = 0; jt < 4; jt++) {
        int p = jt * 16 + l15 + tap * D;
        int cs = c0 ^ ((p & 15) << 3);
        bfr[jt] = *(const h8*)&hl[p * 128 + cs];
      }
#pragma unroll
      for (int i2 = 0; i2 < 2; i2++)
#pragma unroll
        for (int jt = 0; jt < 4; jt++)
          acc[i2][jt] = __builtin_amdgcn_mfma_f32_16x16x32_f16(
              a[i2], bfr[jt], acc[i2][jt], 0, 0, 0);
    }
  }

  _Float16* outN = out + (size_t)n * (TLEN * CCH);
  const _Float16* resN = res ? res + (size_t)n * (TLEN * CCH) : nullptr;
#pragma unroll
  for (int i2 = 0; i2 < 2; i2++) {
    int o = o0 + i2 * 16 + lh * 4;
    f4 bv = {};
    if (bias) bv = *(const f4*)&bias[o];
#pragma unroll
    for (int jt = 0; jt < 4; jt++) {
      int t = t0 + jt * 16 + l15;
      f4 v = acc[i2][jt];
      float z[4];
#pragma unroll
      for (int rr = 0; rr < 4; rr++) z[rr] = fmaxf(v[rr] + bv[rr], 0.f);
      if (mode == 1) {
        h4 rv = *(const h4*)&resN[t * 128 + o];
#pragma unroll
        for (int rr = 0; rr < 4; rr++) z[rr] = fmaxf(z[rr] + (float)rv[rr], 0.f);
      }
      h4 sv;
#pragma unroll
      for (int rr = 0; rr < 4; rr++) sv[rr] = (_Float16)z[rr];
      *(h4*)&outN[t * 128 + o] = sv;
    }
  }
}

// ---------------------------------------------------------------------------
// Final linear via MFMA: out[n][t][o] = sum_c h[t][c]*linW[o][c] + lin_b[o]
__global__ __launch_bounds__(256) void k_mlinear(const _Float16* __restrict__ in,
                                                 float* __restrict__ out,
                                                 const _Float16* __restrict__ wh,
                                                 const float* __restrict__ bias) {
  __shared__ _Float16 Wl[128 * 128];   // 32 KB
  __shared__ _Float16 hl[64 * 128];    // 16 KB
  const int tid = threadIdx.x;
  const int n = blockIdx.y, t0 = blockIdx.x * 64;
  const _Float16* inN = in + (size_t)n * (TLEN * CCH);

  for (int f = tid; f < 2048; f += 256) {
    int row = f >> 4, l16 = f & 15;
    int c8 = (l16 ^ (row & 15)) << 3;
    gload16h(wh + row * 128 + c8, Wl + f * 8);
  }
  for (int f = tid; f < 1024; f += 256) {
    int p = f >> 4, l16 = f & 15;
    int c8 = (l16 ^ (p & 15)) << 3;
    gload16h(inN + (t0 + p) * 128 + c8, hl + f * 8);
  }
  __syncthreads();

  const int l = tid & 63, w = tid >> 6;
  const int l15 = l & 15, lh = l >> 4;
  const int o0 = w * 32;
  f4 acc[2][4] = {};

#pragma unroll
  for (int cb = 0; cb < 4; cb++) {
    const int c0 = cb * 32 + 8 * lh;
    h8 a[2], bfr[4];
#pragma unroll
    for (int i2 = 0; i2 < 2; i2++) {
      int o = o0 + i2 * 16 + l15;
      int cs = c0 ^ ((o & 15) << 3);
      a[i2] = *(const h8*)&Wl[o * 128 + cs];
    }
#pragma unroll
    for (int jt = 0; jt < 4; jt++) {
      int p = jt * 16 + l15;
      int cs = c0 ^ ((p & 15) << 3);
      bfr[jt] = *(const h8*)&hl[p * 128 + cs];
    }
#pragma unroll
    for (int i2 = 0; i2 < 2; i2++)
#pragma unroll
      for (int jt = 0; jt < 4; jt++)
        acc[i2][jt] = __builtin_amdgcn_mfma_f32_16x16x32_f16(
            a[i2], bfr[jt], acc[i2][jt], 0, 0, 0);
  }

#pragma unroll
  for (int i2 = 0; i2 < 2; i2++) {
    int o = o0 + i2 * 16 + lh * 4;
    f4 bv = *(const f4*)&bias[o];
#pragma unroll
    for (int jt = 0; jt < 4; jt++) {
      int t = t0 + jt * 16 + l15;
      f4 v = acc[i2][jt];
      float4 sv = make_float4(v[0] + bv[0], v[1] + bv[1], v[2] + bv[2], v[3] + bv[3]);
      *(float4*)&out[((size_t)n * TLEN + t) * CCH + o] = sv;
    }
  }
}

// ---------------------------------------------------------------------------
extern "C" void kernel_launch(void* const* d_in, const int* in_sizes, int n_in,
                              void* d_out, int out_size, void* d_ws, size_t ws_size,
                              hipStream_t stream) {
  const float* x  = (const float*)d_in[0];
  const float* r  = (const float*)d_in[1];
  // d_in[2] = f_out_same_in_size (==1)
  const float* w1 = (const float*)d_in[3];
  const float* b1 = (const float*)d_in[4];
  const float* w2 = (const float*)d_in[5];
  const float* b2 = (const float*)d_in[6];
  const float* fW = (const float*)d_in[7];
  const float* fb = (const float*)d_in[8];
  const float* lb = (const float*)d_in[9];
  const float* lw = (const float*)d_in[10];
  const float* lbias = (const float*)d_in[11];
  float* out = (float*)d_out;

  _Float16* h0    = (_Float16*)d_ws;        // 2,097,152 halves
  _Float16* h1    = h0 + 2097152;           // 2,097,152
  _Float16* Wsh   = h1 + 2097152;           // 393,216
  _Float16* linWh = Wsh + 393216;           // 16,384
  _Float16* Wg    = linWh + 16384;          // 1,572,864  (total ~12.4 MB)

  k_cast<<<1024, 256, 0, stream>>>(x, h0);
  k_prep_w<<<768, 256, 0, stream>>>(w1, w2, lw, Wsh, linWh);
  k_genh<<<3072, 256, 0, stream>>>(r, fW, fb, lb, Wg);

  const dim3 cg(16, 16);
  // shared blocks: conv1 (mode0, b1) then conv2 (mode1, b2, res)
  k_mconv<1><<<cg, 256, 0, stream>>>(h0, h1, nullptr, Wsh + 0 * 32768, 0, b1 + 0 * 128, 0);
  k_mconv<1><<<cg, 256, 0, stream>>>(h1, h0, h0,      Wsh + 3 * 32768, 0, b2 + 0 * 128, 1);
  k_mconv<2><<<cg, 256, 0, stream>>>(h0, h1, nullptr, Wsh + 1 * 32768, 0, b1 + 1 * 128, 0);
  k_mconv<2><<<cg, 256, 0, stream>>>(h1, h0, h0,      Wsh + 4 * 32768, 0, b2 + 1 * 128, 1);
  k_mconv<4><<<cg, 256, 0, stream>>>(h0, h1, nullptr, Wsh + 2 * 32768, 0, b1 + 2 * 128, 0);
  k_mconv<4><<<cg, 256, 0, stream>>>(h1, h0, h0,      Wsh + 5 * 32768, 0, b2 + 2 * 128, 1);
  // group blocks: conv i, batch n uses Wg + (16i+n)*32768 halves
  k_mconv<8> <<<cg, 256, 0, stream>>>(h0, h1, h0, Wg + (size_t)0 * 16 * 32768, 32768, nullptr, 1);
  k_mconv<16><<<cg, 256, 0, stream>>>(h1, h0, h1, Wg + (size_t)1 * 16 * 32768, 32768, nullptr, 1);
  k_mconv<32><<<cg, 256, 0, stream>>>(h0, h1, h0, Wg + (size_t)2 * 16 * 32768, 32768, nullptr, 1);

  k_mlinear<<<cg, 256, 0, stream>>>(h1, out, linWh, lbias);
}

// Round 6
// 128.833 us; speedup vs baseline: 5.5192x; 1.0241x over previous
//
#include <hip/hip_runtime.h>

// Problem constants
#define NB    16
#define TLEN  1024
#define CCH   128
#define DR    320
#define GENL  98304    // 3*128*128*2

typedef _Float16 h8 __attribute__((ext_vector_type(8)));
typedef _Float16 h4 __attribute__((ext_vector_type(4)));
typedef float    f4 __attribute__((ext_vector_type(4)));

// async global->LDS, 16 B/lane (linear lane->LDS mapping; swizzle goes on the
// GLOBAL source address, LDS dest stays linear — guide §5/m173 pattern)
__device__ __forceinline__ void gload16h(const _Float16* g, _Float16* l) {
  __builtin_amdgcn_global_load_lds(
      (const __attribute__((address_space(1))) void*)g,
      (__attribute__((address_space(3))) void*)l, 16, 0, 0);
}
__device__ __forceinline__ void gload16f(const float* g, float* l) {
  __builtin_amdgcn_global_load_lds(
      (const __attribute__((address_space(1))) void*)g,
      (__attribute__((address_space(3))) void*)l, 16, 0, 0);
}

// ---------------------------------------------------------------------------
// x (N,T,C) fp32 -> h0 (N,T,C) fp16  (pure cast; layout already t-major)
__global__ __launch_bounds__(256) void k_cast(const float* __restrict__ x,
                                              _Float16* __restrict__ h) {
  int i = blockIdx.x * 256 + threadIdx.x;     // 262144 threads, 8 elems each
  const float4* src = (const float4*)x + (size_t)i * 2;
  float4 a = src[0], b = src[1];
  h8 v;
  v[0] = (_Float16)a.x; v[1] = (_Float16)a.y; v[2] = (_Float16)a.z; v[3] = (_Float16)a.w;
  v[4] = (_Float16)b.x; v[5] = (_Float16)b.y; v[6] = (_Float16)b.z; v[7] = (_Float16)b.w;
  *(h8*)(h + (size_t)i * 8) = v;
}

// ---------------------------------------------------------------------------
// Shared conv weights [i][o][c][k] fp32 -> Wsh[i][o][k][c] fp16; lin_W -> fp16
__global__ __launch_bounds__(256) void k_prep_w(const float* __restrict__ w1,
                                                const float* __restrict__ w2,
                                                const float* __restrict__ linw,
                                                _Float16* __restrict__ Wsh,
                                                _Float16* __restrict__ linWh) {
  int idx = blockIdx.x * 256 + threadIdx.x;
  if (idx < 6 * 32768) {
    int c = idx & 127, k = (idx >> 7) & 1, o = (idx >> 8) & 127, i = idx >> 15;
    const float* src = (i < 3) ? (w1 + i * 32768) : (w2 + (i - 3) * 32768);
    Wsh[idx] = (_Float16)src[(o * 128 + c) * 2 + k];
  }
  if (idx < 16384) linWh[idx] = (_Float16)linw[idx];
}

// ---------------------------------------------------------------------------
// gen = r @ fparam_W^T + fb + lb -> Wg[q][o][k][c] fp16, q = 3n+G (= 16i+m).
// Streaming GEMM, m97 pattern: 256 blocks x 384 rows, 12 tiles of 32 rows,
// LDS double-buffered via global_load_lds (async, 40 KB in flight per CU),
// one barrier per tile. 8 lanes per row; 3-level shfl_xor reduce.
__global__ __launch_bounds__(256) void k_gen2(const float* __restrict__ r,
                                              const float* __restrict__ fW,
                                              const float* __restrict__ fb,
                                              const float* __restrict__ lb,
                                              _Float16* __restrict__ wg) {
  __shared__ alignas(16) float rl[NB * DR];        // 20 KB
  __shared__ alignas(16) float buf[2][32 * DR];    // 2 x 40 KB
  const int tid = threadIdx.x;
  const int bid = blockIdx.x;
  const size_t base = (size_t)bid * 384;           // first fW row of this block

  for (int f = tid; f < NB * DR / 4; f += 256)
    ((float4*)rl)[f] = ((const float4*)r)[f];

  {  // stage tile 0
    const float* src = fW + base * DR;
    for (int f = tid; f < 2560; f += 256) gload16f(src + f * 4, &buf[0][f * 4]);
  }
  __syncthreads();

  const int row = tid >> 3, l = tid & 7;

  for (int j = 0; j < 12; j++) {
    if (j < 11) {  // issue next tile's async loads; they land during compute
      const float* src = fW + (base + (size_t)(j + 1) * 32) * DR;
      float* dst = buf[(j + 1) & 1];
      for (int f = tid; f < 2560; f += 256) gload16f(src + f * 4, dst + f * 4);
    }
    const float* rowp = &buf[j & 1][row * DR + l * 4];
    float acc[16];
#pragma unroll
    for (int n = 0; n < 16; n++) acc[n] = 0.f;
#pragma unroll
    for (int s = 0; s < 10; s++) {
      float4 wv = *(const float4*)(rowp + s * 32);
#pragma unroll
      for (int n = 0; n < 16; n++) {
        float4 rv = *(const float4*)&rl[n * DR + l * 4 + s * 32];
        acc[n] += wv.x * rv.x + wv.y * rv.y + wv.z * rv.z + wv.w * rv.w;
      }
    }
#pragma unroll
    for (int m = 1; m <= 4; m <<= 1)
#pragma unroll
      for (int n = 0; n < 16; n++) acc[n] += __shfl_xor(acc[n], m, 64);

    const unsigned g = (unsigned)(base + j * 32 + row);
    const float add = fb[g] + lb[g];
    const unsigned G = g >> 15, o = (g >> 8) & 127u, c = (g & 255u) >> 1, k = g & 1u;
#pragma unroll
    for (int jj = 0; jj < 2; jj++) {
      int n = l * 2 + jj;
      unsigned q = 3u * (unsigned)n + G;
      wg[(((size_t)q * 128 + o) * 2 + k) * 128 + c] = (_Float16)(acc[n] + add);
    }
    __syncthreads();  // tile j+1 landed; everyone done with buf[j&1]
  }
}

// ---------------------------------------------------------------------------
// MFMA causal K=2 dilated conv. h layout [n][t][c] fp16, W [o][tap][c] fp16.
// Block = one n, 64-t tile, 256 thr (4 waves, each 32 o x 64 t).
// GEMM: C[o,t] = sum_{tap,c} W[o][tap][c] * H[t - (1-tap)*D][c], K = tap*128+c.
// A and B fragments use the SAME (lane>>4, j)->k packing rule, so the HW
// k-permutation cancels. C/D: col=lane&15 (t), row=(lane>>4)*4+reg (o).
// LDS XOR-swizzle c ^ ((row&15)<<3); applied on the global source for staging.
template <int D>
__global__ __launch_bounds__(256) void k_mconv(const _Float16* __restrict__ in,
                                               _Float16* __restrict__ out,
                                               const _Float16* __restrict__ res,
                                               const _Float16* __restrict__ wBase,
                                               size_t wStrideN,
                                               const float* __restrict__ bias,
                                               int mode) {
  __shared__ _Float16 Wl[256 * 128];         // [o][tap][c] 64 KB
  __shared__ _Float16 hl[(64 + D) * 128];    // rows p: t = t0 - D + p
  const int tid = threadIdx.x;
  const int n = blockIdx.y, t0 = blockIdx.x * 64;
  const _Float16* inN = in + (size_t)n * (TLEN * CCH);
  const _Float16* wp = wBase + (size_t)n * wStrideN;

  // stage W: 256 rows (o*2+tap) x 16 chunks of 16 B, source pre-swizzled
  for (int f = tid; f < 4096; f += 256) {
    int row = f >> 4, l16 = f & 15;
    int c8 = (l16 ^ ((row >> 1) & 15)) << 3;
    gload16h(wp + row * 128 + c8, Wl + f * 8);
  }
  // stage h rows
  if (blockIdx.x == 0) {
    for (int f = tid; f < D * 16; f += 256)
      *(int4*)((char*)hl + (size_t)f * 16) = make_int4(0, 0, 0, 0);
    for (int f = D * 16 + tid; f < (64 + D) * 16; f += 256) {
      int p = f >> 4, l16 = f & 15;
      int c8 = (l16 ^ (p & 15)) << 3;
      gload16h(inN + (t0 - D + p) * 128 + c8, hl + f * 8);
    }
  } else {
    for (int f = tid; f < (64 + D) * 16; f += 256) {
      int p = f >> 4, l16 = f & 15;
      int c8 = (l16 ^ (p & 15)) << 3;
      gload16h(inN + (t0 - D + p) * 128 + c8, hl + f * 8);
    }
  }
  __syncthreads();

  const int l = tid & 63, w = tid >> 6;
  const int l15 = l & 15, lh = l >> 4;
  const int o0 = w * 32;
  f4 acc[2][4] = {};

#pragma unroll
  for (int tap = 0; tap < 2; tap++) {
#pragma unroll
    for (int cb = 0; cb < 4; cb++) {
      const int c0 = cb * 32 + 8 * lh;   // this lane's logical 8-c block
      h8 a[2], bfr[4];
#pragma unroll
      for (int i2 = 0; i2 < 2; i2++) {
        int o = o0 + i2 * 16 + l15;
        int cs = c0 ^ ((o & 15) << 3);
        a[i2] = *(const h8*)&Wl[(o * 2 + tap) * 128 + cs];
      }
#pragma unroll
      for (int jt = 0; jt < 4; jt++) {
        int p = jt * 16 + l15 + tap * D;
        int cs = c0 ^ ((p & 15) << 3);
        bfr[jt] = *(const h8*)&hl[p * 128 + cs];
      }
#pragma unroll
      for (int i2 = 0; i2 < 2; i2++)
#pragma unroll
        for (int jt = 0; jt < 4; jt++)
          acc[i2][jt] = __builtin_amdgcn_mfma_f32_16x16x32_f16(
              a[i2], bfr[jt], acc[i2][jt], 0, 0, 0);
    }
  }

  _Float16* outN = out + (size_t)n * (TLEN * CCH);
  const _Float16* resN = res ? res + (size_t)n * (TLEN * CCH) : nullptr;
#pragma unroll
  for (int i2 = 0; i2 < 2; i2++) {
    int o = o0 + i2 * 16 + lh * 4;
    f4 bv = {};
    if (bias) bv = *(const f4*)&bias[o];
#pragma unroll
    for (int jt = 0; jt < 4; jt++) {
      int t = t0 + jt * 16 + l15;
      f4 v = acc[i2][jt];
      float z[4];
#pragma unroll
      for (int rr = 0; rr < 4; rr++) z[rr] = fmaxf(v[rr] + bv[rr], 0.f);
      if (mode == 1) {
        h4 rv = *(const h4*)&resN[t * 128 + o];
#pragma unroll
        for (int rr = 0; rr < 4; rr++) z[rr] = fmaxf(z[rr] + (float)rv[rr], 0.f);
      }
      h4 sv;
#pragma unroll
      for (int rr = 0; rr < 4; rr++) sv[rr] = (_Float16)z[rr];
      *(h4*)&outN[t * 128 + o] = sv;
    }
  }
}

// ---------------------------------------------------------------------------
// Final linear via MFMA: out[n][t][o] = sum_c h[t][c]*linW[o][c] + lin_b[o]
__global__ __launch_bounds__(256) void k_mlinear(const _Float16* __restrict__ in,
                                                 float* __restrict__ out,
                                                 const _Float16* __restrict__ wh,
                                                 const float* __restrict__ bias) {
  __shared__ _Float16 Wl[128 * 128];   // 32 KB
  __shared__ _Float16 hl[64 * 128];    // 16 KB
  const int tid = threadIdx.x;
  const int n = blockIdx.y, t0 = blockIdx.x * 64;
  const _Float16* inN = in + (size_t)n * (TLEN * CCH);

  for (int f = tid; f < 2048; f += 256) {
    int row = f >> 4, l16 = f & 15;
    int c8 = (l16 ^ (row & 15)) << 3;
    gload16h(wh + row * 128 + c8, Wl + f * 8);
  }
  for (int f = tid; f < 1024; f += 256) {
    int p = f >> 4, l16 = f & 15;
    int c8 = (l16 ^ (p & 15)) << 3;
    gload16h(inN + (t0 + p) * 128 + c8, hl + f * 8);
  }
  __syncthreads();

  const int l = tid & 63, w = tid >> 6;
  const int l15 = l & 15, lh = l >> 4;
  const int o0 = w * 32;
  f4 acc[2][4] = {};

#pragma unroll
  for (int cb = 0; cb < 4; cb++) {
    const int c0 = cb * 32 + 8 * lh;
    h8 a[2], bfr[4];
#pragma unroll
    for (int i2 = 0; i2 < 2; i2++) {
      int o = o0 + i2 * 16 + l15;
      int cs = c0 ^ ((o & 15) << 3);
      a[i2] = *(const h8*)&Wl[o * 128 + cs];
    }
#pragma unroll
    for (int jt = 0; jt < 4; jt++) {
      int p = jt * 16 + l15;
      int cs = c0 ^ ((p & 15) << 3);
      bfr[jt] = *(const h8*)&hl[p * 128 + cs];
    }
#pragma unroll
    for (int i2 = 0; i2 < 2; i2++)
#pragma unroll
      for (int jt = 0; jt < 4; jt++)
        acc[i2][jt] = __builtin_amdgcn_mfma_f32_16x16x32_f16(
            a[i2], bfr[jt], acc[i2][jt], 0, 0, 0);
  }

#pragma unroll
  for (int i2 = 0; i2 < 2; i2++) {
    int o = o0 + i2 * 16 + lh * 4;
    f4 bv = *(const f4*)&bias[o];
#pragma unroll
    for (int jt = 0; jt < 4; jt++) {
      int t = t0 + jt * 16 + l15;
      f4 v = acc[i2][jt];
      float4 sv = make_float4(v[0] + bv[0], v[1] + bv[1], v[2] + bv[2], v[3] + bv[3]);
      *(float4*)&out[((size_t)n * TLEN + t) * CCH + o] = sv;
    }
  }
}

// ---------------------------------------------------------------------------
extern "C" void kernel_launch(void* const* d_in, const int* in_sizes, int n_in,
                              void* d_out, int out_size, void* d_ws, size_t ws_size,
                              hipStream_t stream) {
  const float* x  = (const float*)d_in[0];
  const float* r  = (const float*)d_in[1];
  // d_in[2] = f_out_same_in_size (==1)
  const float* w1 = (const float*)d_in[3];
  const float* b1 = (const float*)d_in[4];
  const float* w2 = (const float*)d_in[5];
  const float* b2 = (const float*)d_in[6];
  const float* fW = (const float*)d_in[7];
  const float* fb = (const float*)d_in[8];
  const float* lb = (const float*)d_in[9];
  const float* lw = (const float*)d_in[10];
  const float* lbias = (const float*)d_in[11];
  float* out = (float*)d_out;

  _Float16* h0    = (_Float16*)d_ws;        // 2,097,152 halves
  _Float16* h1    = h0 + 2097152;           // 2,097,152
  _Float16* Wsh   = h1 + 2097152;           // 393,216
  _Float16* linWh = Wsh + 393216;           // 16,384
  _Float16* Wg    = linWh + 16384;          // 1,572,864  (total ~12.4 MB)

  k_cast<<<1024, 256, 0, stream>>>(x, h0);
  k_prep_w<<<768, 256, 0, stream>>>(w1, w2, lw, Wsh, linWh);
  k_gen2<<<256, 256, 0, stream>>>(r, fW, fb, lb, Wg);

  const dim3 cg(16, 16);
  // shared blocks: conv1 (mode0, b1) then conv2 (mode1, b2, res)
  k_mconv<1><<<cg, 256, 0, stream>>>(h0, h1, nullptr, Wsh + 0 * 32768, 0, b1 + 0 * 128, 0);
  k_mconv<1><<<cg, 256, 0, stream>>>(h1, h0, h0,      Wsh + 3 * 32768, 0, b2 + 0 * 128, 1);
  k_mconv<2><<<cg, 256, 0, stream>>>(h0, h1, nullptr, Wsh + 1 * 32768, 0, b1 + 1 * 128, 0);
  k_mconv<2><<<cg, 256, 0, stream>>>(h1, h0, h0,      Wsh + 4 * 32768, 0, b2 + 1 * 128, 1);
  k_mconv<4><<<cg, 256, 0, stream>>>(h0, h1, nullptr, Wsh + 2 * 32768, 0, b1 + 2 * 128, 0);
  k_mconv<4><<<cg, 256, 0, stream>>>(h1, h0, h0,      Wsh + 5 * 32768, 0, b2 + 2 * 128, 1);
  // group blocks: conv i, batch n uses Wg + (16i+n)*32768 halves
  k_mconv<8> <<<cg, 256, 0, stream>>>(h0, h1, h0, Wg + (size_t)0 * 16 * 32768, 32768, nullptr, 1);
  k_mconv<16><<<cg, 256, 0, stream>>>(h1, h0, h1, Wg + (size_t)1 * 16 * 32768, 32768, nullptr, 1);
  k_mconv<32><<<cg, 256, 0, stream>>>(h0, h1, h0, Wg + (size_t)2 * 16 * 32768, 32768, nullptr, 1);

  k_mlinear<<<cg, 256, 0, stream>>>(h1, out, linWh, lbias);
}

// Round 9
// 95.020 us; speedup vs baseline: 7.4832x; 1.3559x over previous
//
#include <hip/hip_runtime.h>

// Problem constants
#define NB    16
#define TLEN  1024
#define CCH   128
#define DR    320
#define GENL  98304    // 3*128*128*2

typedef _Float16 h8 __attribute__((ext_vector_type(8)));
typedef _Float16 h4 __attribute__((ext_vector_type(4)));
typedef float    f4 __attribute__((ext_vector_type(4)));

// async global->LDS, 16 B/lane. HW semantics: LDS dest = readfirstlane(base)
// + lane*16, LINEAR — per-lane LDS addresses are ignored, so the staging
// layout must be exactly linear in wave-lane order (rule #21 / m173).
__device__ __forceinline__ void gload16h(const _Float16* g, _Float16* l) {
  __builtin_amdgcn_global_load_lds(
      (const __attribute__((address_space(1))) void*)g,
      (__attribute__((address_space(3))) void*)l, 16, 0, 0);
}
__device__ __forceinline__ void gload16f(const float* g, float* l) {
  __builtin_amdgcn_global_load_lds(
      (const __attribute__((address_space(1))) void*)g,
      (__attribute__((address_space(3))) void*)l, 16, 0, 0);
}
__device__ __forceinline__ void gload4f(const float* g, float* l) {
  __builtin_amdgcn_global_load_lds(
      (const __attribute__((address_space(1))) void*)g,
      (__attribute__((address_space(3))) void*)l, 4, 0, 0);
}

// ---------------------------------------------------------------------------
// x (N,T,C) fp32 -> h0 (N,T,C) fp16  (pure cast; layout already t-major)
__global__ __launch_bounds__(256) void k_cast(const float* __restrict__ x,
                                              _Float16* __restrict__ h) {
  int i = blockIdx.x * 256 + threadIdx.x;
  const float4* src = (const float4*)x + (size_t)i * 2;
  float4 a = src[0], b = src[1];
  h8 v;
  v[0] = (_Float16)a.x; v[1] = (_Float16)a.y; v[2] = (_Float16)a.z; v[3] = (_Float16)a.w;
  v[4] = (_Float16)b.x; v[5] = (_Float16)b.y; v[6] = (_Float16)b.z; v[7] = (_Float16)b.w;
  *(h8*)(h + (size_t)i * 8) = v;
}

// ---------------------------------------------------------------------------
// Shared conv weights [i][o][c][k] fp32 -> Wsh[i][o][k][c] fp16; lin_W -> fp16
__global__ __launch_bounds__(256) void k_prep_w(const float* __restrict__ w1,
                                                const float* __restrict__ w2,
                                                const float* __restrict__ linw,
                                                _Float16* __restrict__ Wsh,
                                                _Float16* __restrict__ linWh) {
  int idx = blockIdx.x * 256 + threadIdx.x;
  if (idx < 6 * 32768) {
    int c = idx & 127, k = (idx >> 7) & 1, o = (idx >> 8) & 127, i = idx >> 15;
    const float* src = (i < 3) ? (w1 + i * 32768) : (w2 + (i - 3) * 32768);
    Wsh[idx] = (_Float16)src[(o * 128 + c) * 2 + k];
  }
  if (idx < 16384) linWh[idx] = (_Float16)linw[idx];
}

// ---------------------------------------------------------------------------
// gen = r @ fparam_W^T + fb + lb -> Wg[q][o][k][c] fp16, q = 3n+G.
// MFMA tall-skinny GEMM: 256 blocks x 384 fW rows, 12 tiles of 32 rows.
// fW staged f32 in LDS (LINEAR, stride 320 — global_load_lds requires it)
// via double-buffer; r cast to f16 B-fragments held in registers.
// 4 waves = 2 row-tiles x 2 k-halves; per-tile LDS k-reduce + coalesced repack.
// Raw s_barrier + explicit waitcnt; B2 is LDS-only so prefetch stays in flight.
__global__ __launch_bounds__(256) void k_gen3(const float* __restrict__ r,
                                              const float* __restrict__ fW,
                                              const float* __restrict__ fb,
                                              const float* __restrict__ lb,
                                              _Float16* __restrict__ wg) {
  __shared__ alignas(16) float rl[16 * DR];        // 20 KB, linear [n][320]
  __shared__ alignas(16) float buf[2][32 * DR];    // 2 x 40 KB, linear [row][320]
  __shared__ alignas(16) float csc[4][16][16];     // 4 KB  k-split partials
  __shared__ float fbsc[32], lbsc[32];
  const int tid = threadIdx.x;
  const size_t rbase = (size_t)blockIdx.x * 384;

  // prologue: stage rl, tile0, tile1 — all destinations exactly linear (f*16 B)
#pragma unroll
  for (int i = 0; i < 5; i++) {
    int f = tid + i * 256;                       // 1280 float4 of r
    gload16f(r + (size_t)f * 4, rl + (size_t)f * 4);
  }
  {
    const float* s0 = fW + rbase * DR;
#pragma unroll
    for (int i = 0; i < 10; i++) {
      int f = tid + i * 256;                     // 2560 float4 per tile
      gload16f(s0 + (size_t)f * 4, (float*)buf[0] + (size_t)f * 4);
    }
    const float* s1 = fW + (rbase + 32) * DR;
#pragma unroll
    for (int i = 0; i < 10; i++) {
      int f = tid + i * 256;
      gload16f(s1 + (size_t)f * 4, (float*)buf[1] + (size_t)f * 4);
    }
  }
  asm volatile("s_waitcnt vmcnt(0) lgkmcnt(0)" ::: "memory");
  __builtin_amdgcn_s_barrier();
  __builtin_amdgcn_sched_barrier(0);

  const int l = tid & 63, w = tid >> 6;
  const int l15 = l & 15, lh = l >> 4;
  const int rt = w >> 1, kh = w & 1;

  // B-fragments: r[n=l15][k = kh*160 + cb*32 + lh*8 + j], f16, in registers
  h8 bfr[5];
#pragma unroll
  for (int cb = 0; cb < 5; cb++) {
    const float* p = &rl[l15 * DR + kh * 160 + cb * 32 + lh * 8];
    f4 x = *(const f4*)p, y = *(const f4*)(p + 4);
    h8 v;
    v[0] = (_Float16)x[0]; v[1] = (_Float16)x[1]; v[2] = (_Float16)x[2]; v[3] = (_Float16)x[3];
    v[4] = (_Float16)y[0]; v[5] = (_Float16)y[1]; v[6] = (_Float16)y[2]; v[7] = (_Float16)y[3];
    bfr[cb] = v;
  }

  for (int j = 0; j < 12; j++) {
    const float* bp = buf[j & 1];
    const int g32 = (int)rbase + j * 32;        // first fW row of this tile

    // fb/lb for this tile -> LDS (async; lanes 0..31 of wave 0, dest linear)
    if (tid < 32) {
      gload4f(fb + g32 + tid, &fbsc[0]);
      gload4f(lb + g32 + tid, &lbsc[0]);
    }

    // MFMA: A = fW rows [rt*16+l15][k], f32->f16 on the fly
    f4 acc = {0.f, 0.f, 0.f, 0.f};
    const float* arow = bp + (rt * 16 + l15) * DR + kh * 160 + lh * 8;
#pragma unroll
    for (int cb = 0; cb < 5; cb++) {
      f4 x = *(const f4*)(arow + cb * 32);
      f4 y = *(const f4*)(arow + cb * 32 + 4);
      h8 a;
      a[0] = (_Float16)x[0]; a[1] = (_Float16)x[1]; a[2] = (_Float16)x[2]; a[3] = (_Float16)x[3];
      a[4] = (_Float16)y[0]; a[5] = (_Float16)y[1]; a[6] = (_Float16)y[2]; a[7] = (_Float16)y[3];
      acc = __builtin_amdgcn_mfma_f32_16x16x32_f16(a, bfr[cb], acc, 0, 0, 0);
    }
    // C partial (row-local lh*4+rr within this row-tile, col n=l15) -> scratch
#pragma unroll
    for (int rr = 0; rr < 4; rr++) csc[w][lh * 4 + rr][l15] = acc[rr];

    // B1: tile j+1 + fb/lb landed, csc visible
    asm volatile("s_waitcnt vmcnt(0) lgkmcnt(0)" ::: "memory");
    __builtin_amdgcn_s_barrier();
    __builtin_amdgcn_sched_barrier(0);

    // repack: 128 threads; per (n,k,cq) sum k-halves, add fb+lb, store 8 B
    if (tid < 128) {
      int n = tid >> 3, k = (tid >> 2) & 1, cq = tid & 3;
      unsigned g = (unsigned)g32;
      unsigned G = g >> 15, o = (g >> 8) & 127u, c0 = (g & 255u) >> 1;
      h4 v;
#pragma unroll
      for (int i = 0; i < 4; i++) {
        int rl32 = (cq * 4 + i) * 2 + k;        // row-local 0..31
        int hp = (rl32 >> 4) * 2, rr = rl32 & 15;
        float s = csc[hp][rr][n] + csc[hp + 1][rr][n] + fbsc[rl32] + lbsc[rl32];
        v[i] = (_Float16)s;
      }
      unsigned q = 3u * (unsigned)n + G;
      *(h4*)&wg[(((size_t)q * 128 + o) * 2 + k) * 128 + c0 + cq * 4] = v;
    }

    // issue tile j+2 into the buffer just retired (dest linear)
    if (j + 2 < 12) {
      float* dst = (float*)buf[j & 1];
      const float* src = fW + (rbase + (size_t)(j + 2) * 32) * DR;
#pragma unroll
      for (int i = 0; i < 10; i++) {
        int f = tid + i * 256;
        gload16f(src + (size_t)f * 4, dst + (size_t)f * 4);
      }
    }

    // B2: LDS-only fence (csc/repack reuse); DMA stays in flight
    asm volatile("s_waitcnt lgkmcnt(0)" ::: "memory");
    __builtin_amdgcn_s_barrier();
    __builtin_amdgcn_sched_barrier(0);
  }
}

// ---------------------------------------------------------------------------
// MFMA causal K=2 dilated conv (unchanged, verified r5/r6).
template <int D>
__global__ __launch_bounds__(256) void k_mconv(const _Float16* __restrict__ in,
                                               _Float16* __restrict__ out,
                                               const _Float16* __restrict__ res,
                                               const _Float16* __restrict__ wBase,
                                               size_t wStrideN,
                                               const float* __restrict__ bias,
                                               int mode) {
  __shared__ _Float16 Wl[256 * 128];         // [o][tap][c] 64 KB
  __shared__ _Float16 hl[(64 + D) * 128];    // rows p: t = t0 - D + p
  const int tid = threadIdx.x;
  const int n = blockIdx.y, t0 = blockIdx.x * 64;
  const _Float16* inN = in + (size_t)n * (TLEN * CCH);
  const _Float16* wp = wBase + (size_t)n * wStrideN;

  for (int f = tid; f < 4096; f += 256) {
    int row = f >> 4, l16 = f & 15;
    int c8 = (l16 ^ ((row >> 1) & 15)) << 3;
    gload16h(wp + row * 128 + c8, Wl + f * 8);
  }
  if (blockIdx.x == 0) {
    for (int f = tid; f < D * 16; f += 256)
      *(int4*)((char*)hl + (size_t)f * 16) = make_int4(0, 0, 0, 0);
    for (int f = D * 16 + tid; f < (64 + D) * 16; f += 256) {
      int p = f >> 4, l16 = f & 15;
      int c8 = (l16 ^ (p & 15)) << 3;
      gload16h(inN + (t0 - D + p) * 128 + c8, hl + f * 8);
    }
  } else {
    for (int f = tid; f < (64 + D) * 16; f += 256) {
      int p = f >> 4, l16 = f & 15;
      int c8 = (l16 ^ (p & 15)) << 3;
      gload16h(inN + (t0 - D + p) * 128 + c8, hl + f * 8);
    }
  }
  __syncthreads();

  const int l = tid & 63, w = tid >> 6;
  const int l15 = l & 15, lh = l >> 4;
  const int o0 = w * 32;
  f4 acc[2][4] = {};

#pragma unroll
  for (int tap = 0; tap < 2; tap++) {
#pragma unroll
    for (int cb = 0; cb < 4; cb++) {
      const int c0 = cb * 32 + 8 * lh;
      h8 a[2], bfr[4];
#pragma unroll
      for (int i2 = 0; i2 < 2; i2++) {
        int o = o0 + i2 * 16 + l15;
        int cs = c0 ^ ((o & 15) << 3);
        a[i2] = *(const h8*)&Wl[(o * 2 + tap) * 128 + cs];
      }
#pragma unroll
      for (int jt = 0; jt < 4; jt++) {
        int p = jt * 16 + l15 + tap * D;
        int cs = c0 ^ ((p & 15) << 3);
        bfr[jt] = *(const h8*)&hl[p * 128 + cs];
      }
#pragma unroll
      for (int i2 = 0; i2 < 2; i2++)
#pragma unroll
        for (int jt = 0; jt < 4; jt++)
          acc[i2][jt] = __builtin_amdgcn_mfma_f32_16x16x32_f16(
              a[i2], bfr[jt], acc[i2][jt], 0, 0, 0);
    }
  }

  _Float16* outN = out + (size_t)n * (TLEN * CCH);
  const _Float16* resN = res ? res + (size_t)n * (TLEN * CCH) : nullptr;
#pragma unroll
  for (int i2 = 0; i2 < 2; i2++) {
    int o = o0 + i2 * 16 + lh * 4;
    f4 bv = {};
    if (bias) bv = *(const f4*)&bias[o];
#pragma unroll
    for (int jt = 0; jt < 4; jt++) {
      int t = t0 + jt * 16 + l15;
      f4 v = acc[i2][jt];
      float z[4];
#pragma unroll
      for (int rr = 0; rr < 4; rr++) z[rr] = fmaxf(v[rr] + bv[rr], 0.f);
      if (mode == 1) {
        h4 rv = *(const h4*)&resN[t * 128 + o];
#pragma unroll
        for (int rr = 0; rr < 4; rr++) z[rr] = fmaxf(z[rr] + (float)rv[rr], 0.f);
      }
      h4 sv;
#pragma unroll
      for (int rr = 0; rr < 4; rr++) sv[rr] = (_Float16)z[rr];
      *(h4*)&outN[t * 128 + o] = sv;
    }
  }
}

// ---------------------------------------------------------------------------
// Final linear via MFMA (unchanged, verified r5/r6).
__global__ __launch_bounds__(256) void k_mlinear(const _Float16* __restrict__ in,
                                                 float* __restrict__ out,
                                                 const _Float16* __restrict__ wh,
                                                 const float* __restrict__ bias) {
  __shared__ _Float16 Wl[128 * 128];
  __shared__ _Float16 hl[64 * 128];
  const int tid = threadIdx.x;
  const int n = blockIdx.y, t0 = blockIdx.x * 64;
  const _Float16* inN = in + (size_t)n * (TLEN * CCH);

  for (int f = tid; f < 2048; f += 256) {
    int row = f >> 4, l16 = f & 15;
    int c8 = (l16 ^ (row & 15)) << 3;
    gload16h(wh + row * 128 + c8, Wl + f * 8);
  }
  for (int f = tid; f < 1024; f += 256) {
    int p = f >> 4, l16 = f & 15;
    int c8 = (l16 ^ (p & 15)) << 3;
    gload16h(inN + (t0 + p) * 128 + c8, hl + f * 8);
  }
  __syncthreads();

  const int l = tid & 63, w = tid >> 6;
  const int l15 = l & 15, lh = l >> 4;
  const int o0 = w * 32;
  f4 acc[2][4] = {};

#pragma unroll
  for (int cb = 0; cb < 4; cb++) {
    const int c0 = cb * 32 + 8 * lh;
    h8 a[2], bfr[4];
#pragma unroll
    for (int i2 = 0; i2 < 2; i2++) {
      int o = o0 + i2 * 16 + l15;
      int cs = c0 ^ ((o & 15) << 3);
      a[i2] = *(const h8*)&Wl[o * 128 + cs];
    }
#pragma unroll
    for (int jt = 0; jt < 4; jt++) {
      int p = jt * 16 + l15;
      int cs = c0 ^ ((p & 15) << 3);
      bfr[jt] = *(const h8*)&hl[p * 128 + cs];
    }
#pragma unroll
    for (int i2 = 0; i2 < 2; i2++)
#pragma unroll
      for (int jt = 0; jt < 4; jt++)
        acc[i2][jt] = __builtin_amdgcn_mfma_f32_16x16x32_f16(
            a[i2], bfr[jt], acc[i2][jt], 0, 0, 0);
  }

#pragma unroll
  for (int i2 = 0; i2 < 2; i2++) {
    int o = o0 + i2 * 16 + lh * 4;
    f4 bv = *(const f4*)&bias[o];
#pragma unroll
    for (int jt = 0; jt < 4; jt++) {
      int t = t0 + jt * 16 + l15;
      f4 v = acc[i2][jt];
      float4 sv = make_float4(v[0] + bv[0], v[1] + bv[1], v[2] + bv[2], v[3] + bv[3]);
      *(float4*)&out[((size_t)n * TLEN + t) * CCH + o] = sv;
    }
  }
}

// ---------------------------------------------------------------------------
extern "C" void kernel_launch(void* const* d_in, const int* in_sizes, int n_in,
                              void* d_out, int out_size, void* d_ws, size_t ws_size,
                              hipStream_t stream) {
  const float* x  = (const float*)d_in[0];
  const float* r  = (const float*)d_in[1];
  // d_in[2] = f_out_same_in_size (==1)
  const float* w1 = (const float*)d_in[3];
  const float* b1 = (const float*)d_in[4];
  const float* w2 = (const float*)d_in[5];
  const float* b2 = (const float*)d_in[6];
  const float* fW = (const float*)d_in[7];
  const float* fb = (const float*)d_in[8];
  const float* lb = (const float*)d_in[9];
  const float* lw = (const float*)d_in[10];
  const float* lbias = (const float*)d_in[11];
  float* out = (float*)d_out;

  _Float16* h0    = (_Float16*)d_ws;        // 2,097,152 halves
  _Float16* h1    = h0 + 2097152;           // 2,097,152
  _Float16* Wsh   = h1 + 2097152;           // 393,216
  _Float16* linWh = Wsh + 393216;           // 16,384
  _Float16* Wg    = linWh + 16384;          // 1,572,864

  k_cast<<<1024, 256, 0, stream>>>(x, h0);
  k_prep_w<<<768, 256, 0, stream>>>(w1, w2, lw, Wsh, linWh);
  k_gen3<<<256, 256, 0, stream>>>(r, fW, fb, lb, Wg);

  const dim3 cg(16, 16);
  k_mconv<1><<<cg, 256, 0, stream>>>(h0, h1, nullptr, Wsh + 0 * 32768, 0, b1 + 0 * 128, 0);
  k_mconv<1><<<cg, 256, 0, stream>>>(h1, h0, h0,      Wsh + 3 * 32768, 0, b2 + 0 * 128, 1);
  k_mconv<2><<<cg, 256, 0, stream>>>(h0, h1, nullptr, Wsh + 1 * 32768, 0, b1 + 1 * 128, 0);
  k_mconv<2><<<cg, 256, 0, stream>>>(h1, h0, h0,      Wsh + 4 * 32768, 0, b2 + 1 * 128, 1);
  k_mconv<4><<<cg, 256, 0, stream>>>(h0, h1, nullptr, Wsh + 2 * 32768, 0, b1 + 2 * 128, 0);
  k_mconv<4><<<cg, 256, 0, stream>>>(h1, h0, h0,      Wsh + 5 * 32768, 0, b2 + 2 * 128, 1);
  k_mconv<8> <<<cg, 256, 0, stream>>>(h0, h1, h0, Wg + (size_t)0 * 16 * 32768, 32768, nullptr, 1);
  k_mconv<16><<<cg, 256, 0, stream>>>(h1, h0, h1, Wg + (size_t)1 * 16 * 32768, 32768, nullptr, 1);
  k_mconv<32><<<cg, 256, 0, stream>>>(h0, h1, h0, Wg + (size_t)2 * 16 * 32768, 32768, nullptr, 1);

  k_mlinear<<<cg, 256, 0, stream>>>(h1, out, linWh, lbias);
}

// Round 10
// 81.689 us; speedup vs baseline: 8.7044x; 1.1632x over previous
//
#include <hip/hip_runtime.h>

// Problem constants
#define NB    16
#define TLEN  1024
#define CCH   128
#define DR    320
#define GENL  98304    // 3*128*128*2

typedef _Float16 h8 __attribute__((ext_vector_type(8)));
typedef _Float16 h4 __attribute__((ext_vector_type(4)));
typedef float    f4 __attribute__((ext_vector_type(4)));

// async global->LDS, 16 B/lane. LDS dest = readfirstlane(base)+lane*16, LINEAR.
__device__ __forceinline__ void gload16h(const _Float16* g, _Float16* l) {
  __builtin_amdgcn_global_load_lds(
      (const __attribute__((address_space(1))) void*)g,
      (__attribute__((address_space(3))) void*)l, 16, 0, 0);
}
__device__ __forceinline__ void gload16f(const float* g, float* l) {
  __builtin_amdgcn_global_load_lds(
      (const __attribute__((address_space(1))) void*)g,
      (__attribute__((address_space(3))) void*)l, 16, 0, 0);
}
__device__ __forceinline__ void gload4f(const float* g, float* l) {
  __builtin_amdgcn_global_load_lds(
      (const __attribute__((address_space(1))) void*)g,
      (__attribute__((address_space(3))) void*)l, 4, 0, 0);
}

// ---------------------------------------------------------------------------
// x (N,T,C) fp32 -> h0 (N,T,C) fp16
__global__ __launch_bounds__(256) void k_cast(const float* __restrict__ x,
                                              _Float16* __restrict__ h) {
  int i = blockIdx.x * 256 + threadIdx.x;
  const float4* src = (const float4*)x + (size_t)i * 2;
  float4 a = src[0], b = src[1];
  h8 v;
  v[0] = (_Float16)a.x; v[1] = (_Float16)a.y; v[2] = (_Float16)a.z; v[3] = (_Float16)a.w;
  v[4] = (_Float16)b.x; v[5] = (_Float16)b.y; v[6] = (_Float16)b.z; v[7] = (_Float16)b.w;
  *(h8*)(h + (size_t)i * 8) = v;
}

// ---------------------------------------------------------------------------
// Shared conv weights [i][o][c][k] fp32 -> Wsh[i][o][k][c] fp16; lin_W -> fp16
__global__ __launch_bounds__(256) void k_prep_w(const float* __restrict__ w1,
                                                const float* __restrict__ w2,
                                                const float* __restrict__ linw,
                                                _Float16* __restrict__ Wsh,
                                                _Float16* __restrict__ linWh) {
  int idx = blockIdx.x * 256 + threadIdx.x;
  if (idx < 6 * 32768) {
    int c = idx & 127, k = (idx >> 7) & 1, o = (idx >> 8) & 127, i = idx >> 15;
    const float* src = (i < 3) ? (w1 + i * 32768) : (w2 + (i - 3) * 32768);
    Wsh[idx] = (_Float16)src[(o * 128 + c) * 2 + k];
  }
  if (idx < 16384) linWh[idx] = (_Float16)linw[idx];
}

// ---------------------------------------------------------------------------
// gen GEMM via MFMA (verified r9): 256 blocks x 384 fW rows, 12 tiles of 32.
__global__ __launch_bounds__(256) void k_gen3(const float* __restrict__ r,
                                              const float* __restrict__ fW,
                                              const float* __restrict__ fb,
                                              const float* __restrict__ lb,
                                              _Float16* __restrict__ wg) {
  __shared__ alignas(16) float rl[16 * DR];
  __shared__ alignas(16) float buf[2][32 * DR];
  __shared__ alignas(16) float csc[4][16][16];
  __shared__ float fbsc[32], lbsc[32];
  const int tid = threadIdx.x;
  const size_t rbase = (size_t)blockIdx.x * 384;

#pragma unroll
  for (int i = 0; i < 5; i++) {
    int f = tid + i * 256;
    gload16f(r + (size_t)f * 4, rl + (size_t)f * 4);
  }
  {
    const float* s0 = fW + rbase * DR;
#pragma unroll
    for (int i = 0; i < 10; i++) {
      int f = tid + i * 256;
      gload16f(s0 + (size_t)f * 4, (float*)buf[0] + (size_t)f * 4);
    }
    const float* s1 = fW + (rbase + 32) * DR;
#pragma unroll
    for (int i = 0; i < 10; i++) {
      int f = tid + i * 256;
      gload16f(s1 + (size_t)f * 4, (float*)buf[1] + (size_t)f * 4);
    }
  }
  asm volatile("s_waitcnt vmcnt(0) lgkmcnt(0)" ::: "memory");
  __builtin_amdgcn_s_barrier();
  __builtin_amdgcn_sched_barrier(0);

  const int l = tid & 63, w = tid >> 6;
  const int l15 = l & 15, lh = l >> 4;
  const int rt = w >> 1, kh = w & 1;

  h8 bfr[5];
#pragma unroll
  for (int cb = 0; cb < 5; cb++) {
    const float* p = &rl[l15 * DR + kh * 160 + cb * 32 + lh * 8];
    f4 x = *(const f4*)p, y = *(const f4*)(p + 4);
    h8 v;
    v[0] = (_Float16)x[0]; v[1] = (_Float16)x[1]; v[2] = (_Float16)x[2]; v[3] = (_Float16)x[3];
    v[4] = (_Float16)y[0]; v[5] = (_Float16)y[1]; v[6] = (_Float16)y[2]; v[7] = (_Float16)y[3];
    bfr[cb] = v;
  }

  for (int j = 0; j < 12; j++) {
    const float* bp = buf[j & 1];
    const int g32 = (int)rbase + j * 32;

    if (tid < 32) {
      gload4f(fb + g32 + tid, &fbsc[0]);
      gload4f(lb + g32 + tid, &lbsc[0]);
    }

    f4 acc = {0.f, 0.f, 0.f, 0.f};
    const float* arow = bp + (rt * 16 + l15) * DR + kh * 160 + lh * 8;
#pragma unroll
    for (int cb = 0; cb < 5; cb++) {
      f4 x = *(const f4*)(arow + cb * 32);
      f4 y = *(const f4*)(arow + cb * 32 + 4);
      h8 a;
      a[0] = (_Float16)x[0]; a[1] = (_Float16)x[1]; a[2] = (_Float16)x[2]; a[3] = (_Float16)x[3];
      a[4] = (_Float16)y[0]; a[5] = (_Float16)y[1]; a[6] = (_Float16)y[2]; a[7] = (_Float16)y[3];
      acc = __builtin_amdgcn_mfma_f32_16x16x32_f16(a, bfr[cb], acc, 0, 0, 0);
    }
#pragma unroll
    for (int rr = 0; rr < 4; rr++) csc[w][lh * 4 + rr][l15] = acc[rr];

    asm volatile("s_waitcnt vmcnt(0) lgkmcnt(0)" ::: "memory");
    __builtin_amdgcn_s_barrier();
    __builtin_amdgcn_sched_barrier(0);

    if (tid < 128) {
      int n = tid >> 3, k = (tid >> 2) & 1, cq = tid & 3;
      unsigned g = (unsigned)g32;
      unsigned G = g >> 15, o = (g >> 8) & 127u, c0 = (g & 255u) >> 1;
      h4 v;
#pragma unroll
      for (int i = 0; i < 4; i++) {
        int rl32 = (cq * 4 + i) * 2 + k;
        int hp = (rl32 >> 4) * 2, rr = rl32 & 15;
        float s = csc[hp][rr][n] + csc[hp + 1][rr][n] + fbsc[rl32] + lbsc[rl32];
        v[i] = (_Float16)s;
      }
      unsigned q = 3u * (unsigned)n + G;
      *(h4*)&wg[(((size_t)q * 128 + o) * 2 + k) * 128 + c0 + cq * 4] = v;
    }

    if (j + 2 < 12) {
      float* dst = (float*)buf[j & 1];
      const float* src = fW + (rbase + (size_t)(j + 2) * 32) * DR;
#pragma unroll
      for (int i = 0; i < 10; i++) {
        int f = tid + i * 256;
        gload16f(src + (size_t)f * 4, dst + (size_t)f * 4);
      }
    }

    asm volatile("s_waitcnt lgkmcnt(0)" ::: "memory");
    __builtin_amdgcn_s_barrier();
    __builtin_amdgcn_sched_barrier(0);
  }
}

// ---------------------------------------------------------------------------
// Fused shared residual pair: a = relu(conv1(h)+b1); a2 = relu(conv2(a)+b2);
// out = relu(a2 + h). conv1 recomputed on [t0-16, t0+64) into LDS; weights
// read per-lane from L2-hot global (no LDS W staging); residual from hin LDS.
// For blockIdx.x==0, a-rows at t<0 are forced to ZERO (reference pads a).
template <int D>   // 1, 2, 4
__global__ __launch_bounds__(256) void k_pair(const _Float16* __restrict__ in,
                                              _Float16* __restrict__ out,
                                              const _Float16* __restrict__ w1p,
                                              const _Float16* __restrict__ w2p,
                                              const float* __restrict__ b1p,
                                              const float* __restrict__ b2p) {
  constexpr int HA = 16;        // a-tile halo (1 col-tile)
  constexpr int HI = HA + D;    // hin halo
  constexpr int RIN = 80 + D;   // hin rows: t = t0 - HI + p
  __shared__ _Float16 hin_l[RIN * 128];  // <= 21.5 KB
  __shared__ _Float16 a_l[80 * 128];     // 20 KB  rows: t = t0 - 16 + p

  const int tid = threadIdx.x;
  const int n = blockIdx.y, t0 = blockIdx.x * 64;
  const _Float16* inN = in + (size_t)n * (TLEN * CCH);

  if (blockIdx.x == 0) {
    for (int f = tid; f < HI * 16; f += 256)
      *(int4*)(hin_l + (size_t)f * 8) = make_int4(0, 0, 0, 0);
    for (int f = HI * 16 + tid; f < RIN * 16; f += 256) {
      int p = f >> 4, l16 = f & 15;
      int c8 = (l16 ^ (p & 15)) << 3;
      gload16h(inN + (t0 - HI + p) * 128 + c8, hin_l + f * 8);
    }
  } else {
    for (int f = tid; f < RIN * 16; f += 256) {
      int p = f >> 4, l16 = f & 15;
      int c8 = (l16 ^ (p & 15)) << 3;
      gload16h(inN + (t0 - HI + p) * 128 + c8, hin_l + f * 8);
    }
  }
  __syncthreads();

  const int l = tid & 63, w = tid >> 6;
  const int l15 = l & 15, lh = l >> 4;
  const int o0 = w * 32;

  // ---- conv1 over 5 col-tiles [t0-16, t0+64) ----
  f4 acc1[2][5] = {};
#pragma unroll
  for (int tap = 0; tap < 2; tap++) {
#pragma unroll
    for (int cb = 0; cb < 4; cb++) {
      const int c0 = cb * 32 + lh * 8;
      h8 a[2], bfr[5];
#pragma unroll
      for (int i2 = 0; i2 < 2; i2++) {
        int o = o0 + i2 * 16 + l15;
        a[i2] = *(const h8*)&w1p[(o * 2 + tap) * 128 + c0];
      }
#pragma unroll
      for (int jt = 0; jt < 5; jt++) {
        int p = jt * 16 + l15 + tap * D;
        int cs = c0 ^ ((p & 15) << 3);
        bfr[jt] = *(const h8*)&hin_l[p * 128 + cs];
      }
#pragma unroll
      for (int i2 = 0; i2 < 2; i2++)
#pragma unroll
        for (int jt = 0; jt < 5; jt++)
          acc1[i2][jt] = __builtin_amdgcn_mfma_f32_16x16x32_f16(
              a[i2], bfr[jt], acc1[i2][jt], 0, 0, 0);
    }
  }
  // store a = relu(acc1 + b1) (zeros for t<0 on block 0)
#pragma unroll
  for (int i2 = 0; i2 < 2; i2++) {
    f4 bv = *(const f4*)&b1p[o0 + i2 * 16 + lh * 4];
    const int base8 = o0 + i2 * 16 + (lh >> 1) * 8;
    const int sub = (lh & 1) * 4;
#pragma unroll
    for (int jt = 0; jt < 5; jt++) {
      int p = jt * 16 + l15;
      h4 sv;
      if (blockIdx.x == 0 && jt == 0) {
        sv[0] = sv[1] = sv[2] = sv[3] = (_Float16)0.f;
      } else {
        f4 v = acc1[i2][jt];
#pragma unroll
        for (int rr = 0; rr < 4; rr++) sv[rr] = (_Float16)fmaxf(v[rr] + bv[rr], 0.f);
      }
      *(h4*)&a_l[p * 128 + (base8 ^ ((p & 15) << 3)) + sub] = sv;
    }
  }
  __syncthreads();

  // ---- conv2 over 4 col-tiles [t0, t0+64) + residual ----
  f4 acc2[2][4] = {};
#pragma unroll
  for (int tap = 0; tap < 2; tap++) {
#pragma unroll
    for (int cb = 0; cb < 4; cb++) {
      const int c0 = cb * 32 + lh * 8;
      h8 a[2], bfr[4];
#pragma unroll
      for (int i2 = 0; i2 < 2; i2++) {
        int o = o0 + i2 * 16 + l15;
        a[i2] = *(const h8*)&w2p[(o * 2 + tap) * 128 + c0];
      }
#pragma unroll
      for (int jt = 0; jt < 4; jt++) {
        int pa = jt * 16 + l15 + (HA - D) + tap * D;
        int cs = c0 ^ ((pa & 15) << 3);
        bfr[jt] = *(const h8*)&a_l[pa * 128 + cs];
      }
#pragma unroll
      for (int i2 = 0; i2 < 2; i2++)
#pragma unroll
        for (int jt = 0; jt < 4; jt++)
          acc2[i2][jt] = __builtin_amdgcn_mfma_f32_16x16x32_f16(
              a[i2], bfr[jt], acc2[i2][jt], 0, 0, 0);
    }
  }

  _Float16* outN = out + (size_t)n * (TLEN * CCH);
#pragma unroll
  for (int i2 = 0; i2 < 2; i2++) {
    f4 bv = *(const f4*)&b2p[o0 + i2 * 16 + lh * 4];
    const int base8 = o0 + i2 * 16 + (lh >> 1) * 8;
    const int sub = (lh & 1) * 4;
#pragma unroll
    for (int jt = 0; jt < 4; jt++) {
      int t = t0 + jt * 16 + l15;
      int pr = jt * 16 + l15 + HA + D;
      h4 rv = *(const h4*)&hin_l[pr * 128 + (base8 ^ ((pr & 15) << 3)) + sub];
      f4 v = acc2[i2][jt];
      h4 sv;
#pragma unroll
      for (int rr = 0; rr < 4; rr++) {
        float z = fmaxf(v[rr] + bv[rr], 0.f);
        sv[rr] = (_Float16)fmaxf(z + (float)rv[rr], 0.f);
      }
      *(h4*)&outN[t * 128 + o0 + i2 * 16 + lh * 4] = sv;
    }
  }
}

// ---------------------------------------------------------------------------
// Group conv (per-n generated weights), res == in, no bias:
// out = relu(relu(conv(h)) + h). Residual read from hl LDS.
template <int D>   // 8, 16
__global__ __launch_bounds__(256) void k_gconv(const _Float16* __restrict__ in,
                                               _Float16* __restrict__ out,
                                               const _Float16* __restrict__ wBase) {
  __shared__ _Float16 Wl[256 * 128];         // 64 KB
  __shared__ _Float16 hl[(64 + D) * 128];
  const int tid = threadIdx.x;
  const int n = blockIdx.y, t0 = blockIdx.x * 64;
  const _Float16* inN = in + (size_t)n * (TLEN * CCH);
  const _Float16* wp = wBase + (size_t)n * 32768;

  for (int f = tid; f < 4096; f += 256) {
    int row = f >> 4, l16 = f & 15;
    int c8 = (l16 ^ ((row >> 1) & 15)) << 3;
    gload16h(wp + row * 128 + c8, Wl + f * 8);
  }
  if (blockIdx.x == 0) {
    for (int f = tid; f < D * 16; f += 256)
      *(int4*)(hl + (size_t)f * 8) = make_int4(0, 0, 0, 0);
    for (int f = D * 16 + tid; f < (64 + D) * 16; f += 256) {
      int p = f >> 4, l16 = f & 15;
      int c8 = (l16 ^ (p & 15)) << 3;
      gload16h(inN + (t0 - D + p) * 128 + c8, hl + f * 8);
    }
  } else {
    for (int f = tid; f < (64 + D) * 16; f += 256) {
      int p = f >> 4, l16 = f & 15;
      int c8 = (l16 ^ (p & 15)) << 3;
      gload16h(inN + (t0 - D + p) * 128 + c8, hl + f * 8);
    }
  }
  __syncthreads();

  const int l = tid & 63, w = tid >> 6;
  const int l15 = l & 15, lh = l >> 4;
  const int o0 = w * 32;
  f4 acc[2][4] = {};

#pragma unroll
  for (int tap = 0; tap < 2; tap++) {
#pragma unroll
    for (int cb = 0; cb < 4; cb++) {
      const int c0 = cb * 32 + 8 * lh;
      h8 a[2], bfr[4];
#pragma unroll
      for (int i2 = 0; i2 < 2; i2++) {
        int o = o0 + i2 * 16 + l15;
        int cs = c0 ^ ((o & 15) << 3);
        a[i2] = *(const h8*)&Wl[(o * 2 + tap) * 128 + cs];
      }
#pragma unroll
      for (int jt = 0; jt < 4; jt++) {
        int p = jt * 16 + l15 + tap * D;
        int cs = c0 ^ ((p & 15) << 3);
        bfr[jt] = *(const h8*)&hl[p * 128 + cs];
      }
#pragma unroll
      for (int i2 = 0; i2 < 2; i2++)
#pragma unroll
        for (int jt = 0; jt < 4; jt++)
          acc[i2][jt] = __builtin_amdgcn_mfma_f32_16x16x32_f16(
              a[i2], bfr[jt], acc[i2][jt], 0, 0, 0);
    }
  }

  _Float16* outN = out + (size_t)n * (TLEN * CCH);
#pragma unroll
  for (int i2 = 0; i2 < 2; i2++) {
    const int base8 = o0 + i2 * 16 + (lh >> 1) * 8;
    const int sub = (lh & 1) * 4;
#pragma unroll
    for (int jt = 0; jt < 4; jt++) {
      int t = t0 + jt * 16 + l15;
      int pr = jt * 16 + l15 + D;
      h4 rv = *(const h4*)&hl[pr * 128 + (base8 ^ ((pr & 15) << 3)) + sub];
      f4 v = acc[i2][jt];
      h4 sv;
#pragma unroll
      for (int rr = 0; rr < 4; rr++) {
        float z = fmaxf(v[rr], 0.f);
        sv[rr] = (_Float16)fmaxf(z + (float)rv[rr], 0.f);
      }
      *(h4*)&outN[t * 128 + o0 + i2 * 16 + lh * 4] = sv;
    }
  }
}

// ---------------------------------------------------------------------------
// Fused: group conv D=32 (res from hl) -> LDS a-tile -> final linear -> f32 out
__global__ __launch_bounds__(256) void k_glin(const _Float16* __restrict__ in,
                                              float* __restrict__ outp,
                                              const _Float16* __restrict__ wBase,
                                              const _Float16* __restrict__ linWh,
                                              const float* __restrict__ lbias) {
  constexpr int D = 32;
  __shared__ _Float16 Wl[256 * 128];         // 64 KB
  __shared__ _Float16 hl[(64 + D) * 128];    // 24 KB
  __shared__ _Float16 a_l[64 * 128];         // 16 KB
  const int tid = threadIdx.x;
  const int n = blockIdx.y, t0 = blockIdx.x * 64;
  const _Float16* inN = in + (size_t)n * (TLEN * CCH);
  const _Float16* wp = wBase + (size_t)n * 32768;

  for (int f = tid; f < 4096; f += 256) {
    int row = f >> 4, l16 = f & 15;
    int c8 = (l16 ^ ((row >> 1) & 15)) << 3;
    gload16h(wp + row * 128 + c8, Wl + f * 8);
  }
  if (blockIdx.x == 0) {
    for (int f = tid; f < D * 16; f += 256)
      *(int4*)(hl + (size_t)f * 8) = make_int4(0, 0, 0, 0);
    for (int f = D * 16 + tid; f < (64 + D) * 16; f += 256) {
      int p = f >> 4, l16 = f & 15;
      int c8 = (l16 ^ (p & 15)) << 3;
      gload16h(inN + (t0 - D + p) * 128 + c8, hl + f * 8);
    }
  } else {
    for (int f = tid; f < (64 + D) * 16; f += 256) {
      int p = f >> 4, l16 = f & 15;
      int c8 = (l16 ^ (p & 15)) << 3;
      gload16h(inN + (t0 - D + p) * 128 + c8, hl + f * 8);
    }
  }
  __syncthreads();

  const int l = tid & 63, w = tid >> 6;
  const int l15 = l & 15, lh = l >> 4;
  const int o0 = w * 32;
  f4 acc[2][4] = {};

#pragma unroll
  for (int tap = 0; tap < 2; tap++) {
#pragma unroll
    for (int cb = 0; cb < 4; cb++) {
      const int c0 = cb * 32 + 8 * lh;
      h8 a[2], bfr[4];
#pragma unroll
      for (int i2 = 0; i2 < 2; i2++) {
        int o = o0 + i2 * 16 + l15;
        int cs = c0 ^ ((o & 15) << 3);
        a[i2] = *(const h8*)&Wl[(o * 2 + tap) * 128 + cs];
      }
#pragma unroll
      for (int jt = 0; jt < 4; jt++) {
        int p = jt * 16 + l15 + tap * D;
        int cs = c0 ^ ((p & 15) << 3);
        bfr[jt] = *(const h8*)&hl[p * 128 + cs];
      }
#pragma unroll
      for (int i2 = 0; i2 < 2; i2++)
#pragma unroll
        for (int jt = 0; jt < 4; jt++)
          acc[i2][jt] = __builtin_amdgcn_mfma_f32_16x16x32_f16(
              a[i2], bfr[jt], acc[i2][jt], 0, 0, 0);
    }
  }

  // epilogue -> a_l (rows = t_local, swizzled like staged layout)
#pragma unroll
  for (int i2 = 0; i2 < 2; i2++) {
    const int base8 = o0 + i2 * 16 + (lh >> 1) * 8;
    const int sub = (lh & 1) * 4;
#pragma unroll
    for (int jt = 0; jt < 4; jt++) {
      int p = jt * 16 + l15;              // t_local; p&15 == l15
      int pr = p + D;
      h4 rv = *(const h4*)&hl[pr * 128 + (base8 ^ ((pr & 15) << 3)) + sub];
      f4 v = acc[i2][jt];
      h4 sv;
#pragma unroll
      for (int rr = 0; rr < 4; rr++) {
        float z = fmaxf(v[rr], 0.f);
        sv[rr] = (_Float16)fmaxf(z + (float)rv[rr], 0.f);
      }
      *(h4*)&a_l[p * 128 + (base8 ^ (l15 << 3)) + sub] = sv;
    }
  }
  __syncthreads();

  // linear: out[n][t][o] = sum_c a[t][c] * linW[o][c] + lin_b[o]
  f4 acc3[2][4] = {};
#pragma unroll
  for (int cb = 0; cb < 4; cb++) {
    const int c0 = cb * 32 + lh * 8;
    h8 a[2], bfr[4];
#pragma unroll
    for (int i2 = 0; i2 < 2; i2++) {
      int o = o0 + i2 * 16 + l15;
      a[i2] = *(const h8*)&linWh[o * 128 + c0];
    }
#pragma unroll
    for (int jt = 0; jt < 4; jt++) {
      int p = jt * 16 + l15;
      int cs = c0 ^ ((p & 15) << 3);
      bfr[jt] = *(const h8*)&a_l[p * 128 + cs];
    }
#pragma unroll
    for (int i2 = 0; i2 < 2; i2++)
#pragma unroll
      for (int jt = 0; jt < 4; jt++)
        acc3[i2][jt] = __builtin_amdgcn_mfma_f32_16x16x32_f16(
            a[i2], bfr[jt], acc3[i2][jt], 0, 0, 0);
  }

#pragma unroll
  for (int i2 = 0; i2 < 2; i2++) {
    int o = o0 + i2 * 16 + lh * 4;
    f4 bv = *(const f4*)&lbias[o];
#pragma unroll
    for (int jt = 0; jt < 4; jt++) {
      int t = t0 + jt * 16 + l15;
      f4 v = acc3[i2][jt];
      float4 sv = make_float4(v[0] + bv[0], v[1] + bv[1], v[2] + bv[2], v[3] + bv[3]);
      *(float4*)&outp[((size_t)n * TLEN + t) * CCH + o] = sv;
    }
  }
}

// ---------------------------------------------------------------------------
extern "C" void kernel_launch(void* const* d_in, const int* in_sizes, int n_in,
                              void* d_out, int out_size, void* d_ws, size_t ws_size,
                              hipStream_t stream) {
  const float* x  = (const float*)d_in[0];
  const float* r  = (const float*)d_in[1];
  // d_in[2] = f_out_same_in_size (==1)
  const float* w1 = (const float*)d_in[3];
  const float* b1 = (const float*)d_in[4];
  const float* w2 = (const float*)d_in[5];
  const float* b2 = (const float*)d_in[6];
  const float* fW = (const float*)d_in[7];
  const float* fb = (const float*)d_in[8];
  const float* lb = (const float*)d_in[9];
  const float* lw = (const float*)d_in[10];
  const float* lbias = (const float*)d_in[11];
  float* out = (float*)d_out;

  _Float16* h0    = (_Float16*)d_ws;        // 2,097,152 halves
  _Float16* h1    = h0 + 2097152;           // 2,097,152
  _Float16* Wsh   = h1 + 2097152;           // 393,216
  _Float16* linWh = Wsh + 393216;           // 16,384
  _Float16* Wg    = linWh + 16384;          // 1,572,864

  k_cast<<<1024, 256, 0, stream>>>(x, h0);
  k_prep_w<<<768, 256, 0, stream>>>(w1, w2, lw, Wsh, linWh);
  k_gen3<<<256, 256, 0, stream>>>(r, fW, fb, lb, Wg);

  const dim3 cg(16, 16);
  k_pair<1><<<cg, 256, 0, stream>>>(h0, h1, Wsh + 0 * 32768, Wsh + 3 * 32768,
                                    b1 + 0 * 128, b2 + 0 * 128);
  k_pair<2><<<cg, 256, 0, stream>>>(h1, h0, Wsh + 1 * 32768, Wsh + 4 * 32768,
                                    b1 + 1 * 128, b2 + 1 * 128);
  k_pair<4><<<cg, 256, 0, stream>>>(h0, h1, Wsh + 2 * 32768, Wsh + 5 * 32768,
                                    b1 + 2 * 128, b2 + 2 * 128);
  // group blocks: conv i, batch n uses Wg + (16i+n)*32768 halves
  k_gconv<8> <<<cg, 256, 0, stream>>>(h1, h0, Wg + (size_t)0 * 16 * 32768);
  k_gconv<16><<<cg, 256, 0, stream>>>(h0, h1, Wg + (size_t)1 * 16 * 32768);
  k_glin<<<cg, 256, 0, stream>>>(h1, out, Wg + (size_t)2 * 16 * 32768, linWh, lbias);
}